// Round 3
// baseline (1984.822 us; speedup 1.0000x reference)
//
#include <hip/hip_runtime.h>
#include <stdint.h>
#include <stddef.h>
#include <math.h>

#define TOKS 4096
#define DM   1024
#define DIP  4384
#define DI   2048
#define CVD  2304
#define NH   32
#define HD   64
#define DST  128
#define NCH  8
#define CHK  256

// ---------------- ws layout (bytes) ----------------
static const size_t OFF_ZX    = 0;                               // float TOKS*DIP
static const size_t OFF_SX    = OFF_ZX + (size_t)TOKS*DIP*4;     // float TOKS*CVD
static const size_t OFF_ST    = OFF_SX + (size_t)TOKS*CVD*4;     // float 2*NCH*NH*HD*DST
static const size_t OFF_YG    = OFF_ST + (size_t)2*NCH*NH*HD*DST*4; // float TOKS*DI
static const size_t OFF_Q1    = OFF_YG + (size_t)TOKS*DI*4;      // i8 TOKS*DM
static const size_t OFF_Q2    = OFF_Q1 + (size_t)TOKS*DM;        // i8 TOKS*DI
static const size_t OFF_WQ1   = OFF_Q2 + (size_t)TOKS*DI;        // i8 DIP*DM
static const size_t OFF_WQ2   = OFF_WQ1 + (size_t)DIP*DM;        // i8 DM*DI
static const size_t OFF_RS1   = OFF_WQ2 + (size_t)DM*DI;         // float TOKS
static const size_t OFF_RS2   = OFF_RS1 + (size_t)TOKS*4;        // float TOKS
static const size_t OFF_DT    = OFF_RS2 + (size_t)TOKS*4;        // float TOKS*NH
static const size_t OFF_ACS   = OFF_DT + (size_t)TOKS*NH*4;      // double 512*CHK
static const size_t OFF_CSUM  = OFF_ACS + (size_t)512*CHK*8;     // double 512
static const size_t OFF_PART  = OFF_CSUM + 512*8;                // double 1024
static const size_t OFF_WSC   = OFF_PART + 1024*8;               // double 2

// ---------------- block reduction helpers (blockDim = 256) ----------------
__device__ __forceinline__ double bsumd(double v, double* sb) {
#pragma unroll
  for (int o = 32; o; o >>= 1) v += __shfl_down(v, o);
  int lane = threadIdx.x & 63, w = threadIdx.x >> 6;
  __syncthreads();
  if (lane == 0) sb[w] = v;
  __syncthreads();
  return sb[0] + sb[1] + sb[2] + sb[3];
}
__device__ __forceinline__ double bmaxd(double v, double* sb) {
#pragma unroll
  for (int o = 32; o; o >>= 1) v = fmax(v, __shfl_down(v, o));
  int lane = threadIdx.x & 63, w = threadIdx.x >> 6;
  __syncthreads();
  if (lane == 0) sb[w] = v;
  __syncthreads();
  return fmax(fmax(sb[0], sb[1]), fmax(sb[2], sb[3]));
}

// ---------------- weight scale (mean |w|), fp64 ----------------
__global__ void __launch_bounds__(256) k_absmean(const float* __restrict__ w, int n, double* __restrict__ part) {
  double s = 0.0;
  for (int i = blockIdx.x * 256 + threadIdx.x; i < n; i += 512 * 256) s += (double)fabsf(w[i]);
  __shared__ double sb[4];
  s = bsumd(s, sb);
  if (threadIdx.x == 0) part[blockIdx.x] = s;
}

__global__ void __launch_bounds__(256) k_wscale(const double* __restrict__ part, double* __restrict__ wsc, int n1, int n2) {
  __shared__ double sb[4];
  double s = part[threadIdx.x] + part[threadIdx.x + 256];
  double t1 = bsumd(s, sb);
  __syncthreads();
  s = part[512 + threadIdx.x] + part[512 + threadIdx.x + 256];
  double t2 = bsumd(s, sb);
  if (threadIdx.x == 0) {
    wsc[0] = fmax(t1 / (double)n1, 1e-5);
    wsc[1] = fmax(t2 / (double)n2, 1e-5);
  }
}

__global__ void __launch_bounds__(256) k_tern(const float* __restrict__ w, int n, const double* __restrict__ wsc, int which, int8_t* __restrict__ out) {
  int i = blockIdx.x * 256 + threadIdx.x;
  if (i < n) {
    double sc = wsc[which];
    double q = fmin(fmax(rint((double)w[i] / sc), -1.0), 1.0);
    out[i] = (int8_t)q;
  }
}

// ---------------- rmsnorm + layernorm + activation quant (decisions in fp64) ----------------
template <int D>
__global__ void __launch_bounds__(256) k_normquant(const float* __restrict__ in, const float* __restrict__ w,
                                                   int8_t* __restrict__ q, float* __restrict__ rs) {
  constexpr int E = D / 256;
  int t = blockIdx.x, tid = threadIdx.x;
  const float* row = in + (size_t)t * D;
  __shared__ double sb[4];
  double x[E];
  double ss = 0.0;
#pragma unroll
  for (int i = 0; i < E; i++) { x[i] = (double)row[tid + 256 * i]; ss += x[i] * x[i]; }
  ss = bsumd(ss, sb);
  double rr = 1.0 / sqrt(ss / (double)D + 1e-6);
  double s1 = 0.0;
#pragma unroll
  for (int i = 0; i < E; i++) { x[i] = (double)w[tid + 256 * i] * (x[i] * rr); s1 += x[i]; }
  s1 = bsumd(s1, sb);
  double mu = s1 / (double)D;
  double s2 = 0.0;
#pragma unroll
  for (int i = 0; i < E; i++) { double d = x[i] - mu; s2 += d * d; }
  s2 = bsumd(s2, sb);
  double rv = 1.0 / sqrt(s2 / (double)D + 1e-5);
  double am = 0.0;
#pragma unroll
  for (int i = 0; i < E; i++) { x[i] = (x[i] - mu) * rv; am = fmax(am, fabs(x[i])); }
  am = bmaxd(am, sb);
  am = fmax(am, 1e-5);
  double sc = 127.0 / am;
#pragma unroll
  for (int i = 0; i < E; i++) {
    double qq = fmin(fmax(rint(x[i] * sc), -128.0), 127.0);
    q[(size_t)t * D + tid + 256 * i] = (int8_t)qq;
  }
  if (tid == 0) rs[t] = (float)(am / 127.0);
}

// ---------------- int8 x ternary GEMM: out[m][n] = rs[m] * sum_k A[m][k]*W[n][k] (+addend) ----------------
__global__ void __launch_bounds__(256) k_gemm_i8(const int8_t* __restrict__ A, const int8_t* __restrict__ W,
                                                 const float* __restrict__ rs, const float* __restrict__ addend,
                                                 float* __restrict__ out, int M, int N, int K) {
  __shared__ float As[64][64];  // [k][m]
  __shared__ float Bs[64][64];  // [k][n]
  int m0 = blockIdx.x * 64, n0 = blockIdx.y * 64;
  int t = threadIdx.x;
  int tx = t & 15, ty = t >> 4;
  int lr = t >> 2, lc = (t & 3) * 16;
  float acc[4][4] = {};
  for (int k0 = 0; k0 < K; k0 += 64) {
    int4 av = *(const int4*)(A + (size_t)(m0 + lr) * K + k0 + lc);
    int4 bv;
    if (n0 + lr < N) bv = *(const int4*)(W + (size_t)(n0 + lr) * K + k0 + lc);
    else { bv.x = bv.y = bv.z = bv.w = 0; }
    const int8_t* ac = (const int8_t*)&av;
    const int8_t* bc = (const int8_t*)&bv;
    __syncthreads();
#pragma unroll
    for (int j = 0; j < 16; j++) {
      As[lc + j][lr] = (float)ac[j];
      Bs[lc + j][lr] = (float)bc[j];
    }
    __syncthreads();
#pragma unroll
    for (int kk = 0; kk < 64; kk++) {
      float4 a4 = *(const float4*)&As[kk][ty * 4];
      float4 b4 = *(const float4*)&Bs[kk][tx * 4];
      float a[4] = {a4.x, a4.y, a4.z, a4.w};
      float b[4] = {b4.x, b4.y, b4.z, b4.w};
#pragma unroll
      for (int i = 0; i < 4; i++)
#pragma unroll
        for (int j = 0; j < 4; j++) acc[i][j] = fmaf(a[i], b[j], acc[i][j]);
    }
  }
#pragma unroll
  for (int i = 0; i < 4; i++) {
    int m = m0 + ty * 4 + i;
    float r = rs[m];
#pragma unroll
    for (int j = 0; j < 4; j++) {
      int n = n0 + tx * 4 + j;
      if (n < N) {
        float v = acc[i][j] * r;
        if (addend) v += addend[(size_t)m * N + n];
        out[(size_t)m * N + n] = v;
      }
    }
  }
}

// ---------------- depthwise causal conv(4) + SiLU ----------------
__global__ void __launch_bounds__(256) k_conv(const float* __restrict__ zx, const float* __restrict__ cw,
                                              const float* __restrict__ cb, float* __restrict__ sx) {
  int c = blockIdx.x * 256 + threadIdx.x;  // 0..2303
  int t = blockIdx.y;                      // 0..4095
  int b = t >> 11, l = t & 2047;
  float acc = cb[c];
#pragma unroll
  for (int k = 0; k < 4; k++) {
    int li = l - 3 + k;
    if (li >= 0) acc = fmaf(zx[(size_t)(b * 2048 + li) * DIP + DI + c], cw[c * 4 + k], acc);
  }
  sx[(size_t)t * CVD + c] = acc / (1.f + expf(-acc)) ;
}

// ---------------- dt = softplus(raw + bias) ----------------
__global__ void __launch_bounds__(256) k_dt(const float* __restrict__ zx, const float* __restrict__ dt_bias,
                                            float* __restrict__ dtv) {
  int idx = blockIdx.x * 256 + threadIdx.x;  // TOKS*NH
  int t = idx >> 5, h = idx & 31;
  float x = zx[(size_t)t * DIP + (DI + CVD) + h] + dt_bias[h];
  dtv[idx] = fmaxf(x, 0.f) + log1pf(expf(-fabsf(x)));
}

// ---------------- per-(b,c,h) cumsum of a = dt * (-exp(A_log)), in fp64 ----------------
__global__ void __launch_bounds__(256) k_cumsum(const float* __restrict__ dtv, const float* __restrict__ A_log,
                                                double* __restrict__ acs, double* __restrict__ csum) {
  int bid = blockIdx.x;  // (b*8+c)*32+h
  int h = bid & 31, bc = bid >> 5;
  int s = threadIdx.x;
  int tok = bc * 256 + s;
  double negA = -exp((double)A_log[h]);
  double a = (double)dtv[tok * 32 + h] * negA;
  __shared__ double buf[256];
  buf[s] = a;
  __syncthreads();
  for (int o = 1; o < 256; o <<= 1) {
    double add = (s >= o) ? buf[s - o] : 0.0;
    __syncthreads();
    buf[s] += add;
    __syncthreads();
  }
  acs[(size_t)bid * 256 + s] = buf[s];
  if (s == 255) csum[bid] = buf[s];
}

// ---------------- per-chunk states: states[p][n] = sum_s B[s,n]*decay[s]*u[s,p] ----------------
__global__ void __launch_bounds__(256) k_states(const float* __restrict__ sx, const float* __restrict__ dtv,
                                                const double* __restrict__ acs, const double* __restrict__ csum,
                                                float* __restrict__ states) {
  int bid = blockIdx.x;  // (b*8+c)*32+h
  int h = bid & 31, bc = bid >> 5;
  int t = threadIdx.x;
  int n = t & 127, ph = t >> 7;
  double last = csum[bid];
  __shared__ float du[64][65];
  float acc[32] = {};
  for (int s0 = 0; s0 < 256; s0 += 64) {
    __syncthreads();
    for (int j = 0; j < 16; j++) {
      int li = t + 256 * j;
      int s = li >> 6, p = li & 63;
      int tok = bc * 256 + s0 + s;
      float decay = expf((float)(last - acs[(size_t)bid * 256 + s0 + s]));
      du[s][p] = sx[(size_t)tok * CVD + h * 64 + p] * dtv[tok * 32 + h] * decay;
    }
    __syncthreads();
    for (int s = 0; s < 64; s++) {
      int tok = bc * 256 + s0 + s;
      float bb = sx[(size_t)tok * CVD + DI + n];
#pragma unroll
      for (int i = 0; i < 32; i++) acc[i] = fmaf(bb, du[s][ph * 32 + i], acc[i]);
    }
  }
  size_t base = (size_t)bid * (HD * DST);
#pragma unroll
  for (int i = 0; i < 32; i++) states[base + (ph * 32 + i) * DST + n] = acc[i];
}

// ---------------- sequential chunk-state recurrence (in-place -> prev_states) ----------------
__global__ void __launch_bounds__(256) k_chunkscan(float* __restrict__ states, const double* __restrict__ csum) {
  int idx = blockIdx.x * 256 + threadIdx.x;  // b,h,p,n  (2*32*64*128)
  int n = idx & 127, p = (idx >> 7) & 63, h = (idx >> 13) & 31, b = idx >> 18;
  float Nv = 0.f;
  for (int c = 0; c < 8; c++) {
    int bid = (b * 8 + c) * 32 + h;
    size_t addr = (size_t)bid * (HD * DST) + p * DST + n;
    float s = states[addr];
    states[addr] = Nv;
    Nv = Nv * expf((float)csum[bid]) + s;
  }
}

// ---------------- fused Y_diag + Y_off + xD + silu(z) gate ----------------
__global__ void __launch_bounds__(256) k_y(const float* __restrict__ sx, const float* __restrict__ dtv,
                                           const double* __restrict__ acs, const float* __restrict__ prev,
                                           const float* __restrict__ zx, const float* __restrict__ Dp,
                                           float* __restrict__ yg) {
  int bid = blockIdx.x;           // (((b*8+c)*32+h)*4 + lt)
  int lt = bid & 3, r = bid >> 2; // r = (b*8+c)*32+h
  int h = r & 31, bc = r >> 5;
  int l0 = lt * 64;
  int t = threadIdx.x;
  int tx = t & 63, g = t >> 6;

  __shared__ float S_l[64][68];
  __shared__ float buf[64 * 129];

  float acc[16] = {};
  const double* acsr = acs + (size_t)r * 256;

  for (int st = 0; st <= lt; st++) {
    int s0 = st * 64;
    __syncthreads();
    // load B tile [s][n], pitch 129
    for (int j = 0; j < 32; j++) {
      int li = t + 256 * j;
      int s = li >> 7, nn = li & 127;
      buf[s * 129 + nn] = sx[(size_t)(bc * 256 + s0 + s) * CVD + DI + nn];
    }
    __syncthreads();
    // S[l][s] = exp(acs[l]-acs[s]) * dot(C[l], B[s])  (masked), exponent diff in fp64
    double a_s = acsr[s0 + tx];
#pragma unroll
    for (int i = 0; i < 16; i++) {
      int ll = g * 16 + i;
      int lg = l0 + ll;
      float v = 0.f;
      if (s0 + tx <= lg) {
        double a_l = acsr[lg];
        const float* Crow = sx + (size_t)(bc * 256 + lg) * CVD + DI + DST;
        float dot = 0.f;
#pragma unroll 8
        for (int nn = 0; nn < 128; nn += 4) {
          float4 cv = *(const float4*)(Crow + nn);
          dot += cv.x * buf[tx * 129 + nn] + cv.y * buf[tx * 129 + nn + 1] +
                 cv.z * buf[tx * 129 + nn + 2] + cv.w * buf[tx * 129 + nn + 3];
        }
        v = expf((float)(a_l - a_s)) * dot;
      }
      S_l[ll][tx] = v;
    }
    __syncthreads();
    // load u tile [s][p], pitch 129
    for (int j = 0; j < 16; j++) {
      int li = t + 256 * j;
      int s = li >> 6, p = li & 63;
      int tok = bc * 256 + s0 + s;
      buf[s * 129 + p] = sx[(size_t)tok * CVD + h * 64 + p] * dtv[tok * 32 + h];
    }
    __syncthreads();
    // acc[l][p] += S[l][s'] * u[s'][p]
    for (int s4 = 0; s4 < 64; s4 += 4) {
      float u0 = buf[(s4 + 0) * 129 + tx];
      float u1 = buf[(s4 + 1) * 129 + tx];
      float u2 = buf[(s4 + 2) * 129 + tx];
      float u3 = buf[(s4 + 3) * 129 + tx];
#pragma unroll
      for (int i = 0; i < 16; i++) {
        const float4 sv = *(const float4*)&S_l[g * 16 + i][s4];
        acc[i] = fmaf(sv.x, u0, fmaf(sv.y, u1, fmaf(sv.z, u2, fmaf(sv.w, u3, acc[i]))));
      }
    }
  }

  // Y_off: load prev[p][n] pitch 129
  __syncthreads();
  for (int j = 0; j < 32; j++) {
    int li = t + 256 * j;
    int p = li >> 7, nn = li & 127;
    buf[p * 129 + nn] = prev[(size_t)r * (HD * DST) + p * DST + nn];
  }
  __syncthreads();
#pragma unroll
  for (int i = 0; i < 16; i++) {
    int lg = l0 + g * 16 + i;
    const float* Crow = sx + (size_t)(bc * 256 + lg) * CVD + DI + DST;
    float dot = 0.f;
#pragma unroll 8
    for (int nn = 0; nn < 128; nn += 4) {
      float4 cv = *(const float4*)(Crow + nn);
      dot += cv.x * buf[tx * 129 + nn] + cv.y * buf[tx * 129 + nn + 1] +
             cv.z * buf[tx * 129 + nn + 2] + cv.w * buf[tx * 129 + nn + 3];
    }
    acc[i] += expf((float)acsr[lg]) * dot;
  }

  // epilogue: + x*Dp, gate by silu(z)
  float dph = Dp[h];
#pragma unroll
  for (int i = 0; i < 16; i++) {
    int lg = l0 + g * 16 + i;
    size_t tok = (size_t)(bc * 256 + lg);
    float xv = sx[tok * CVD + h * 64 + tx];
    float y = acc[i] + xv * dph;
    float z = zx[tok * DIP + h * 64 + tx];
    y *= z / (1.f + expf(-z));
    yg[tok * DI + h * 64 + tx] = y;
  }
}

// ---------------- launch ----------------
extern "C" void kernel_launch(void* const* d_in, const int* in_sizes, int n_in,
                              void* d_out, int out_size, void* d_ws, size_t ws_size,
                              hipStream_t stream) {
  const float* hidden   = (const float*)d_in[0];
  const float* norm_w   = (const float*)d_in[1];
  const float* in_proj  = (const float*)d_in[2];
  const float* conv_w   = (const float*)d_in[3];
  const float* conv_b   = (const float*)d_in[4];
  const float* A_log    = (const float*)d_in[5];
  const float* Dp       = (const float*)d_in[6];
  const float* dt_bias  = (const float*)d_in[7];
  const float* out_norm = (const float*)d_in[8];
  const float* out_proj = (const float*)d_in[9];
  float* out = (float*)d_out;

  char* ws = (char*)d_ws;
  float*  zx    = (float*)(ws + OFF_ZX);
  float*  sx    = (float*)(ws + OFF_SX);
  float*  st    = (float*)(ws + OFF_ST);
  float*  yg    = (float*)(ws + OFF_YG);
  int8_t* q1    = (int8_t*)(ws + OFF_Q1);
  int8_t* q2    = (int8_t*)(ws + OFF_Q2);
  int8_t* wq1   = (int8_t*)(ws + OFF_WQ1);
  int8_t* wq2   = (int8_t*)(ws + OFF_WQ2);
  float*  rs1   = (float*)(ws + OFF_RS1);
  float*  rs2   = (float*)(ws + OFF_RS2);
  float*  dtv   = (float*)(ws + OFF_DT);
  double* acs   = (double*)(ws + OFF_ACS);
  double* csum  = (double*)(ws + OFF_CSUM);
  double* part  = (double*)(ws + OFF_PART);
  double* wsc   = (double*)(ws + OFF_WSC);

  const int n1 = DIP * DM, n2 = DM * DI;

  hipLaunchKernelGGL(k_absmean, dim3(512), dim3(256), 0, stream, in_proj, n1, part);
  hipLaunchKernelGGL(k_absmean, dim3(512), dim3(256), 0, stream, out_proj, n2, part + 512);
  hipLaunchKernelGGL(k_wscale, dim3(1), dim3(256), 0, stream, part, wsc, n1, n2);
  hipLaunchKernelGGL(k_tern, dim3((n1 + 255) / 256), dim3(256), 0, stream, in_proj, n1, wsc, 0, wq1);
  hipLaunchKernelGGL(k_tern, dim3((n2 + 255) / 256), dim3(256), 0, stream, out_proj, n2, wsc, 1, wq2);
  hipLaunchKernelGGL(k_normquant<DM>, dim3(TOKS), dim3(256), 0, stream, hidden, norm_w, q1, rs1);
  hipLaunchKernelGGL(k_gemm_i8, dim3(TOKS / 64, (DIP + 63) / 64), dim3(256), 0, stream,
                     q1, wq1, rs1, (const float*)nullptr, zx, TOKS, DIP, DM);
  hipLaunchKernelGGL(k_conv, dim3(CVD / 256, TOKS), dim3(256), 0, stream, zx, conv_w, conv_b, sx);
  hipLaunchKernelGGL(k_dt, dim3(TOKS * NH / 256), dim3(256), 0, stream, zx, dt_bias, dtv);
  hipLaunchKernelGGL(k_cumsum, dim3(512), dim3(256), 0, stream, dtv, A_log, acs, csum);
  hipLaunchKernelGGL(k_states, dim3(512), dim3(256), 0, stream, sx, dtv, acs, csum, st);
  hipLaunchKernelGGL(k_chunkscan, dim3(2 * NH * HD * DST / 256), dim3(256), 0, stream, st, csum);
  hipLaunchKernelGGL(k_y, dim3(2048), dim3(256), 0, stream, sx, dtv, acs, st, zx, Dp, yg);
  hipLaunchKernelGGL(k_normquant<DI>, dim3(TOKS), dim3(256), 0, stream, yg, out_norm, q2, rs2);
  hipLaunchKernelGGL(k_gemm_i8, dim3(TOKS / 64, DM / 64), dim3(256), 0, stream,
                     q2, wq2, rs2, hidden, out, TOKS, DM, DI);
  (void)in_sizes; (void)n_in; (void)out_size; (void)ws_size;
}

// Round 4
// 591.884 us; speedup vs baseline: 3.3534x; 3.3534x over previous
//
#include <hip/hip_runtime.h>
#include <stdint.h>
#include <stddef.h>
#include <math.h>

#define TOKS 4096
#define DM   1024
#define DIP  4384
#define DI   2048
#define CVD  2304
#define NH   32
#define HD   64
#define DST  128
#define NCH  8
#define CHK  256

typedef int v4i  __attribute__((ext_vector_type(4)));
typedef int v16i __attribute__((ext_vector_type(16)));

// ---------------- ws layout (bytes) ----------------
static const size_t OFF_ZX    = 0;                               // float TOKS*DIP
static const size_t OFF_SX    = OFF_ZX + (size_t)TOKS*DIP*4;     // float TOKS*CVD
static const size_t OFF_ST    = OFF_SX + (size_t)TOKS*CVD*4;     // float 2*NCH*NH*HD*DST
static const size_t OFF_YG    = OFF_ST + (size_t)2*NCH*NH*HD*DST*4; // float TOKS*DI
static const size_t OFF_Q1    = OFF_YG + (size_t)TOKS*DI*4;      // i8 TOKS*DM
static const size_t OFF_Q2    = OFF_Q1 + (size_t)TOKS*DM;        // i8 TOKS*DI
static const size_t OFF_WQ1   = OFF_Q2 + (size_t)TOKS*DI;        // i8 DIP*DM
static const size_t OFF_WQ2   = OFF_WQ1 + (size_t)DIP*DM;        // i8 DM*DI
static const size_t OFF_RS1   = OFF_WQ2 + (size_t)DM*DI;         // float TOKS
static const size_t OFF_RS2   = OFF_RS1 + (size_t)TOKS*4;        // float TOKS
static const size_t OFF_DT    = OFF_RS2 + (size_t)TOKS*4;        // float TOKS*NH
static const size_t OFF_ACS   = OFF_DT + (size_t)TOKS*NH*4;      // double 512*CHK
static const size_t OFF_CSUM  = OFF_ACS + (size_t)512*CHK*8;     // double 512
static const size_t OFF_PART  = OFF_CSUM + 512*8;                // double 1024
static const size_t OFF_WSC   = OFF_PART + 1024*8;               // double 2

// ---------------- block reduction helpers (blockDim = 256) ----------------
__device__ __forceinline__ double bsumd(double v, double* sb) {
#pragma unroll
  for (int o = 32; o; o >>= 1) v += __shfl_down(v, o);
  int lane = threadIdx.x & 63, w = threadIdx.x >> 6;
  __syncthreads();
  if (lane == 0) sb[w] = v;
  __syncthreads();
  return sb[0] + sb[1] + sb[2] + sb[3];
}
__device__ __forceinline__ double bmaxd(double v, double* sb) {
#pragma unroll
  for (int o = 32; o; o >>= 1) v = fmax(v, __shfl_down(v, o));
  int lane = threadIdx.x & 63, w = threadIdx.x >> 6;
  __syncthreads();
  if (lane == 0) sb[w] = v;
  __syncthreads();
  return fmax(fmax(sb[0], sb[1]), fmax(sb[2], sb[3]));
}

// ---------------- weight scale (mean |w|), fp64 ----------------
__global__ void __launch_bounds__(256) k_absmean(const float* __restrict__ w, int n, double* __restrict__ part) {
  double s = 0.0;
  for (int i = blockIdx.x * 256 + threadIdx.x; i < n; i += 512 * 256) s += (double)fabsf(w[i]);
  __shared__ double sb[4];
  s = bsumd(s, sb);
  if (threadIdx.x == 0) part[blockIdx.x] = s;
}

__global__ void __launch_bounds__(256) k_wscale(const double* __restrict__ part, double* __restrict__ wsc, int n1, int n2) {
  __shared__ double sb[4];
  double s = part[threadIdx.x] + part[threadIdx.x + 256];
  double t1 = bsumd(s, sb);
  __syncthreads();
  s = part[512 + threadIdx.x] + part[512 + threadIdx.x + 256];
  double t2 = bsumd(s, sb);
  if (threadIdx.x == 0) {
    wsc[0] = fmax(t1 / (double)n1, 1e-5);
    wsc[1] = fmax(t2 / (double)n2, 1e-5);
  }
}

__global__ void __launch_bounds__(256) k_tern(const float* __restrict__ w, int n, const double* __restrict__ wsc, int which, int8_t* __restrict__ out) {
  int i = blockIdx.x * 256 + threadIdx.x;
  if (i < n) {
    double sc = wsc[which];
    double q = fmin(fmax(rint((double)w[i] / sc), -1.0), 1.0);
    out[i] = (int8_t)q;
  }
}

// ---------------- rmsnorm + layernorm + activation quant (decisions in fp64) ----------------
template <int D>
__global__ void __launch_bounds__(256) k_normquant(const float* __restrict__ in, const float* __restrict__ w,
                                                   int8_t* __restrict__ q, float* __restrict__ rs) {
  constexpr int E = D / 256;
  int t = blockIdx.x, tid = threadIdx.x;
  const float* row = in + (size_t)t * D;
  __shared__ double sb[4];
  double x[E];
  double ss = 0.0;
#pragma unroll
  for (int i = 0; i < E; i++) { x[i] = (double)row[tid + 256 * i]; ss += x[i] * x[i]; }
  ss = bsumd(ss, sb);
  double rr = 1.0 / sqrt(ss / (double)D + 1e-6);
  double s1 = 0.0;
#pragma unroll
  for (int i = 0; i < E; i++) { x[i] = (double)w[tid + 256 * i] * (x[i] * rr); s1 += x[i]; }
  s1 = bsumd(s1, sb);
  double mu = s1 / (double)D;
  double s2 = 0.0;
#pragma unroll
  for (int i = 0; i < E; i++) { double d = x[i] - mu; s2 += d * d; }
  s2 = bsumd(s2, sb);
  double rv = 1.0 / sqrt(s2 / (double)D + 1e-5);
  double am = 0.0;
#pragma unroll
  for (int i = 0; i < E; i++) { x[i] = (x[i] - mu) * rv; am = fmax(am, fabs(x[i])); }
  am = bmaxd(am, sb);
  am = fmax(am, 1e-5);
  double sc = 127.0 / am;
#pragma unroll
  for (int i = 0; i < E; i++) {
    double qq = fmin(fmax(rint(x[i] * sc), -128.0), 127.0);
    q[(size_t)t * D + tid + 256 * i] = (int8_t)qq;
  }
  if (tid == 0) rs[t] = (float)(am / 127.0);
}

// ---------------- int8 x ternary GEMM via MFMA i8 ----------------
// out[m][n] = rs[m] * sum_k A[m][k]*W[n][k] (+addend). 128x128 tile, 4 waves 2x2.
__global__ void __launch_bounds__(256, 3) k_gemm_mfma(const int8_t* __restrict__ A, const int8_t* __restrict__ W,
                                                      const float* __restrict__ rs, const float* __restrict__ addend,
                                                      float* __restrict__ out, int M, int N, int K) {
  __shared__ int8_t Al[128 * 80];  // [m][k] K=64 + 16 pad
  __shared__ int8_t Bl[128 * 80];  // [n][k]
  int m0 = blockIdx.x * 128, n0 = blockIdx.y * 128;
  int t = threadIdx.x;
  int w = t >> 6, lane = t & 63;
  int wm = w >> 1, wn = w & 1;
  int l31 = lane & 31, lh = lane >> 5;

  v16i acc[2][2] = {};

  for (int k0 = 0; k0 < K; k0 += 64) {
    __syncthreads();
#pragma unroll
    for (int it = 0; it < 2; ++it) {
      int c = t + 256 * it;          // 0..511
      int row = c >> 2, kc = (c & 3) * 16;
      // A tile
      int4 av = *(const int4*)(A + (size_t)(m0 + row) * K + k0 + kc);
      *(int4*)(Al + row * 80 + kc) = av;
      // B tile (guard N)
      int4 bv;
      if (n0 + row < N) bv = *(const int4*)(W + (size_t)(n0 + row) * K + k0 + kc);
      else { bv.x = bv.y = bv.z = bv.w = 0; }
      *(int4*)(Bl + row * 80 + kc) = bv;
    }
    __syncthreads();
#pragma unroll
    for (int ks = 0; ks < 2; ++ks) {
      v4i af[2], bf[2];
#pragma unroll
      for (int tm = 0; tm < 2; ++tm)
        af[tm] = *(const v4i*)(Al + (wm * 64 + tm * 32 + l31) * 80 + ks * 32 + lh * 16);
#pragma unroll
      for (int tn = 0; tn < 2; ++tn)
        bf[tn] = *(const v4i*)(Bl + (wn * 64 + tn * 32 + l31) * 80 + ks * 32 + lh * 16);
#pragma unroll
      for (int tm = 0; tm < 2; ++tm)
#pragma unroll
        for (int tn = 0; tn < 2; ++tn)
          acc[tm][tn] = __builtin_amdgcn_mfma_i32_32x32x32_i8(af[tm], bf[tn], acc[tm][tn], 0, 0, 0);
    }
  }

  // epilogue: C/D layout col=lane&31, row=(reg&3)+8*(reg>>2)+4*(lane>>5)
#pragma unroll
  for (int tm = 0; tm < 2; ++tm)
#pragma unroll
    for (int tn = 0; tn < 2; ++tn) {
      int n = n0 + wn * 64 + tn * 32 + l31;
      if (n < N) {
#pragma unroll
        for (int r = 0; r < 16; ++r) {
          int mrel = (r & 3) + 8 * (r >> 2) + 4 * lh;
          int m = m0 + wm * 64 + tm * 32 + mrel;
          float v = rs[m] * (float)acc[tm][tn][r];
          if (addend) v += addend[(size_t)m * N + n];
          out[(size_t)m * N + n] = v;
        }
      }
    }
}

// ---------------- depthwise causal conv(4) + SiLU ----------------
__global__ void __launch_bounds__(256) k_conv(const float* __restrict__ zx, const float* __restrict__ cw,
                                              const float* __restrict__ cb, float* __restrict__ sx) {
  int c = blockIdx.x * 256 + threadIdx.x;  // 0..2303
  int t = blockIdx.y;                      // 0..4095
  int b = t >> 11, l = t & 2047;
  float acc = cb[c];
#pragma unroll
  for (int k = 0; k < 4; k++) {
    int li = l - 3 + k;
    if (li >= 0) acc = fmaf(zx[(size_t)(b * 2048 + li) * DIP + DI + c], cw[c * 4 + k], acc);
  }
  sx[(size_t)t * CVD + c] = acc / (1.f + expf(-acc));
}

// ---------------- dt = softplus(raw + bias) ----------------
__global__ void __launch_bounds__(256) k_dt(const float* __restrict__ zx, const float* __restrict__ dt_bias,
                                            float* __restrict__ dtv) {
  int idx = blockIdx.x * 256 + threadIdx.x;  // TOKS*NH
  int t = idx >> 5, h = idx & 31;
  float x = zx[(size_t)t * DIP + (DI + CVD) + h] + dt_bias[h];
  dtv[idx] = fmaxf(x, 0.f) + log1pf(expf(-fabsf(x)));
}

// ---------------- per-(b,c,h) cumsum of a = dt * (-exp(A_log)), in fp64 ----------------
__global__ void __launch_bounds__(256) k_cumsum(const float* __restrict__ dtv, const float* __restrict__ A_log,
                                                double* __restrict__ acs, double* __restrict__ csum) {
  int bid = blockIdx.x;  // (b*8+c)*32+h
  int h = bid & 31, bc = bid >> 5;
  int s = threadIdx.x;
  int tok = bc * 256 + s;
  double negA = -exp((double)A_log[h]);
  double a = (double)dtv[tok * 32 + h] * negA;
  __shared__ double buf[256];
  buf[s] = a;
  __syncthreads();
  for (int o = 1; o < 256; o <<= 1) {
    double add = (s >= o) ? buf[s - o] : 0.0;
    __syncthreads();
    buf[s] += add;
    __syncthreads();
  }
  acs[(size_t)bid * 256 + s] = buf[s];
  if (s == 255) csum[bid] = buf[s];
}

// ---------------- per-chunk states: states[p][n] = sum_s B[s,n]*decay[s]*u[s,p] ----------------
__global__ void __launch_bounds__(256) k_states(const float* __restrict__ sx, const float* __restrict__ dtv,
                                                const double* __restrict__ acs, const double* __restrict__ csum,
                                                float* __restrict__ states) {
  int bid = blockIdx.x;  // (b*8+c)*32+h
  int h = bid & 31, bc = bid >> 5;
  int t = threadIdx.x;
  int n = t & 127, ph = t >> 7;
  double last = csum[bid];
  __shared__ float du[64][65];
  float acc[32] = {};
  for (int s0 = 0; s0 < 256; s0 += 64) {
    __syncthreads();
    for (int j = 0; j < 16; j++) {
      int li = t + 256 * j;
      int s = li >> 6, p = li & 63;
      int tok = bc * 256 + s0 + s;
      float decay = expf((float)(last - acs[(size_t)bid * 256 + s0 + s]));
      du[s][p] = sx[(size_t)tok * CVD + h * 64 + p] * dtv[tok * 32 + h] * decay;
    }
    __syncthreads();
    for (int s = 0; s < 64; s++) {
      int tok = bc * 256 + s0 + s;
      float bb = sx[(size_t)tok * CVD + DI + n];
#pragma unroll
      for (int i = 0; i < 32; i++) acc[i] = fmaf(bb, du[s][ph * 32 + i], acc[i]);
    }
  }
  size_t base = (size_t)bid * (HD * DST);
#pragma unroll
  for (int i = 0; i < 32; i++) states[base + (ph * 32 + i) * DST + n] = acc[i];
}

// ---------------- sequential chunk-state recurrence (in-place -> prev_states) ----------------
__global__ void __launch_bounds__(256) k_chunkscan(float* __restrict__ states, const double* __restrict__ csum) {
  int idx = blockIdx.x * 256 + threadIdx.x;  // b,h,p,n  (2*32*64*128)
  int n = idx & 127, p = (idx >> 7) & 63, h = (idx >> 13) & 31, b = idx >> 18;
  float Nv = 0.f;
  for (int c = 0; c < 8; c++) {
    int bid = (b * 8 + c) * 32 + h;
    size_t addr = (size_t)bid * (HD * DST) + p * DST + n;
    float s = states[addr];
    states[addr] = Nv;
    Nv = Nv * expf((float)csum[bid]) + s;
  }
}

// ---------------- fused Y_diag + Y_off + xD + silu(z) gate, register-tiled ----------------
__global__ void __launch_bounds__(256, 3) k_y2(const float* __restrict__ sx, const float* __restrict__ dtv,
                                               const double* __restrict__ acs, const float* __restrict__ prev,
                                               const float* __restrict__ zx, const float* __restrict__ Dp,
                                               float* __restrict__ yg) {
  int bid = blockIdx.x;            // (((b*8+c)*32+h)*4 + lt)
  int lt = bid & 3, r = bid >> 2;  // r = (b*8+c)*32+h
  int h = r & 31, bc = r >> 5;
  int l0 = lt * 64;
  int t = threadIdx.x;
  int tx = t & 15, ty = t >> 4;

  __shared__ float Bt[128 * 68];   // B^T [nn][s]; overlaid by u[64][68] and Pt[nn][p]
  __shared__ float Sl[64 * 68];    // S tile [l][s]

  float acc[4][4] = {};
  const double* acsr = acs + (size_t)r * 256;

  int llv[4];
  double a_l[4];
  const float* Crow[4];
#pragma unroll
  for (int j = 0; j < 4; j++) {
    llv[j] = l0 + ty * 4 + j;
    a_l[j] = acsr[llv[j]];
    Crow[j] = sx + (size_t)(bc * 256 + llv[j]) * CVD + DI + DST;
  }

  for (int st = 0; st <= lt; ++st) {
    int s0 = st * 64;
    __syncthreads();
    // stage B^T: Bt[nn][s] = B[s][nn]
    {
      int s = t & 63, nng = t >> 6;
      const float* brow = sx + (size_t)(bc * 256 + s0 + s) * CVD + DI + nng * 32;
#pragma unroll
      for (int i4 = 0; i4 < 8; ++i4) {
        float4 v = *(const float4*)(brow + i4 * 4);
        int nn = nng * 32 + i4 * 4;
        Bt[(nn + 0) * 68 + s] = v.x;
        Bt[(nn + 1) * 68 + s] = v.y;
        Bt[(nn + 2) * 68 + s] = v.z;
        Bt[(nn + 3) * 68 + s] = v.w;
      }
    }
    __syncthreads();
    // GEMM#1: dot[j][jj] = sum_nn C[l_j][nn] * B[s_jj][nn]
    float dotv[4][4] = {};
    for (int nn = 0; nn < 128; nn += 4) {
      float ca[4][4], bb[4][4];
#pragma unroll
      for (int j = 0; j < 4; j++) {
        float4 v = *(const float4*)(Crow[j] + nn);
        ca[j][0] = v.x; ca[j][1] = v.y; ca[j][2] = v.z; ca[j][3] = v.w;
      }
#pragma unroll
      for (int q = 0; q < 4; q++) {
        float4 v = *(const float4*)(&Bt[(nn + q) * 68 + tx * 4]);
        bb[q][0] = v.x; bb[q][1] = v.y; bb[q][2] = v.z; bb[q][3] = v.w;
      }
#pragma unroll
      for (int j = 0; j < 4; j++)
#pragma unroll
        for (int q = 0; q < 4; q++)
#pragma unroll
          for (int jj = 0; jj < 4; jj++)
            dotv[j][jj] = fmaf(ca[j][q], bb[q][jj], dotv[j][jj]);
    }
    // scale by decay, mask, store S
    {
      double a_s[4];
#pragma unroll
      for (int jj = 0; jj < 4; jj++) a_s[jj] = acsr[s0 + tx * 4 + jj];
#pragma unroll
      for (int j = 0; j < 4; j++) {
        float4 sv;
        float vv[4];
#pragma unroll
        for (int jj = 0; jj < 4; jj++) {
          float v = 0.f;
          bool ok = (st < lt) || ((tx * 4 + jj) <= (ty * 4 + j));
          if (ok) v = expf((float)(a_l[j] - a_s[jj])) * dotv[j][jj];
          vv[jj] = v;
        }
        sv.x = vv[0]; sv.y = vv[1]; sv.z = vv[2]; sv.w = vv[3];
        *(float4*)(&Sl[(ty * 4 + j) * 68 + tx * 4]) = sv;
      }
    }
    __syncthreads();
    // stage u[s][p] = x[s][p]*dt[s] into Bt region
    {
      int s = t >> 2, pg = (t & 3) * 16;
      int tok = bc * 256 + s0 + s;
      float dt = dtv[tok * 32 + h];
      const float* xr = sx + (size_t)tok * CVD + h * 64 + pg;
      float* ur = &Bt[s * 68 + pg];
#pragma unroll
      for (int i4 = 0; i4 < 4; ++i4) {
        float4 v = *(const float4*)(xr + i4 * 4);
        v.x *= dt; v.y *= dt; v.z *= dt; v.w *= dt;
        *(float4*)(ur + i4 * 4) = v;
      }
    }
    __syncthreads();
    // GEMM#2: acc[j][jj] += S[l_j][s] * u[s][p_jj]
    for (int s4 = 0; s4 < 64; s4 += 4) {
      float sa[4][4], ua[4][4];
#pragma unroll
      for (int j = 0; j < 4; j++) {
        float4 v = *(const float4*)(&Sl[(ty * 4 + j) * 68 + s4]);
        sa[j][0] = v.x; sa[j][1] = v.y; sa[j][2] = v.z; sa[j][3] = v.w;
      }
#pragma unroll
      for (int q = 0; q < 4; q++) {
        float4 v = *(const float4*)(&Bt[(s4 + q) * 68 + tx * 4]);
        ua[q][0] = v.x; ua[q][1] = v.y; ua[q][2] = v.z; ua[q][3] = v.w;
      }
#pragma unroll
      for (int j = 0; j < 4; j++)
#pragma unroll
        for (int q = 0; q < 4; q++)
#pragma unroll
          for (int jj = 0; jj < 4; jj++)
            acc[j][jj] = fmaf(sa[j][q], ua[q][jj], acc[j][jj]);
    }
  }

  // Y_off: stage Pt[nn][p] = prev[p][nn]
  __syncthreads();
  {
    int p = t >> 2, ng = (t & 3) * 32;
    const float* pr = prev + (size_t)r * (HD * DST) + p * DST + ng;
#pragma unroll
    for (int i4 = 0; i4 < 8; ++i4) {
      float4 v = *(const float4*)(pr + i4 * 4);
      int nn = ng + i4 * 4;
      Bt[(nn + 0) * 68 + p] = v.x;
      Bt[(nn + 1) * 68 + p] = v.y;
      Bt[(nn + 2) * 68 + p] = v.z;
      Bt[(nn + 3) * 68 + p] = v.w;
    }
  }
  __syncthreads();
  {
    float e_l[4];
#pragma unroll
    for (int j = 0; j < 4; j++) e_l[j] = expf((float)a_l[j]);
    for (int nn = 0; nn < 128; nn += 4) {
      float ca[4][4], bb[4][4];
#pragma unroll
      for (int j = 0; j < 4; j++) {
        float4 v = *(const float4*)(Crow[j] + nn);
        ca[j][0] = v.x * e_l[j]; ca[j][1] = v.y * e_l[j]; ca[j][2] = v.z * e_l[j]; ca[j][3] = v.w * e_l[j];
      }
#pragma unroll
      for (int q = 0; q < 4; q++) {
        float4 v = *(const float4*)(&Bt[(nn + q) * 68 + tx * 4]);
        bb[q][0] = v.x; bb[q][1] = v.y; bb[q][2] = v.z; bb[q][3] = v.w;
      }
#pragma unroll
      for (int j = 0; j < 4; j++)
#pragma unroll
        for (int q = 0; q < 4; q++)
#pragma unroll
          for (int jj = 0; jj < 4; jj++)
            acc[j][jj] = fmaf(ca[j][q], bb[q][jj], acc[j][jj]);
    }
  }

  // epilogue: + x*Dp, gate by silu(z)
  float dph = Dp[h];
#pragma unroll
  for (int j = 0; j < 4; j++) {
    size_t tok = (size_t)(bc * 256 + llv[j]);
    float4 xv = *(const float4*)(sx + tok * CVD + h * 64 + tx * 4);
    float4 zv = *(const float4*)(zx + tok * DIP + h * 64 + tx * 4);
    float y0 = acc[j][0] + xv.x * dph;
    float y1 = acc[j][1] + xv.y * dph;
    float y2 = acc[j][2] + xv.z * dph;
    float y3 = acc[j][3] + xv.w * dph;
    float4 o;
    o.x = y0 * (zv.x / (1.f + expf(-zv.x)));
    o.y = y1 * (zv.y / (1.f + expf(-zv.y)));
    o.z = y2 * (zv.z / (1.f + expf(-zv.z)));
    o.w = y3 * (zv.w / (1.f + expf(-zv.w)));
    *(float4*)(yg + tok * DI + h * 64 + tx * 4) = o;
  }
}

// ---------------- launch ----------------
extern "C" void kernel_launch(void* const* d_in, const int* in_sizes, int n_in,
                              void* d_out, int out_size, void* d_ws, size_t ws_size,
                              hipStream_t stream) {
  const float* hidden   = (const float*)d_in[0];
  const float* norm_w   = (const float*)d_in[1];
  const float* in_proj  = (const float*)d_in[2];
  const float* conv_w   = (const float*)d_in[3];
  const float* conv_b   = (const float*)d_in[4];
  const float* A_log    = (const float*)d_in[5];
  const float* Dp       = (const float*)d_in[6];
  const float* dt_bias  = (const float*)d_in[7];
  const float* out_norm = (const float*)d_in[8];
  const float* out_proj = (const float*)d_in[9];
  float* out = (float*)d_out;

  char* ws = (char*)d_ws;
  float*  zx    = (float*)(ws + OFF_ZX);
  float*  sx    = (float*)(ws + OFF_SX);
  float*  st    = (float*)(ws + OFF_ST);
  float*  yg    = (float*)(ws + OFF_YG);
  int8_t* q1    = (int8_t*)(ws + OFF_Q1);
  int8_t* q2    = (int8_t*)(ws + OFF_Q2);
  int8_t* wq1   = (int8_t*)(ws + OFF_WQ1);
  int8_t* wq2   = (int8_t*)(ws + OFF_WQ2);
  float*  rs1   = (float*)(ws + OFF_RS1);
  float*  rs2   = (float*)(ws + OFF_RS2);
  float*  dtv   = (float*)(ws + OFF_DT);
  double* acs   = (double*)(ws + OFF_ACS);
  double* csum  = (double*)(ws + OFF_CSUM);
  double* part  = (double*)(ws + OFF_PART);
  double* wsc   = (double*)(ws + OFF_WSC);

  const int n1 = DIP * DM, n2 = DM * DI;

  hipLaunchKernelGGL(k_absmean, dim3(512), dim3(256), 0, stream, in_proj, n1, part);
  hipLaunchKernelGGL(k_absmean, dim3(512), dim3(256), 0, stream, out_proj, n2, part + 512);
  hipLaunchKernelGGL(k_wscale, dim3(1), dim3(256), 0, stream, part, wsc, n1, n2);
  hipLaunchKernelGGL(k_tern, dim3((n1 + 255) / 256), dim3(256), 0, stream, in_proj, n1, wsc, 0, wq1);
  hipLaunchKernelGGL(k_tern, dim3((n2 + 255) / 256), dim3(256), 0, stream, out_proj, n2, wsc, 1, wq2);
  hipLaunchKernelGGL(k_normquant<DM>, dim3(TOKS), dim3(256), 0, stream, hidden, norm_w, q1, rs1);
  hipLaunchKernelGGL(k_gemm_mfma, dim3(TOKS / 128, (DIP + 127) / 128), dim3(256), 0, stream,
                     q1, wq1, rs1, (const float*)nullptr, zx, TOKS, DIP, DM);
  hipLaunchKernelGGL(k_conv, dim3(CVD / 256, TOKS), dim3(256), 0, stream, zx, conv_w, conv_b, sx);
  hipLaunchKernelGGL(k_dt, dim3(TOKS * NH / 256), dim3(256), 0, stream, zx, dt_bias, dtv);
  hipLaunchKernelGGL(k_cumsum, dim3(512), dim3(256), 0, stream, dtv, A_log, acs, csum);
  hipLaunchKernelGGL(k_states, dim3(512), dim3(256), 0, stream, sx, dtv, acs, csum, st);
  hipLaunchKernelGGL(k_chunkscan, dim3(2 * NH * HD * DST / 256), dim3(256), 0, stream, st, csum);
  hipLaunchKernelGGL(k_y2, dim3(2048), dim3(256), 0, stream, sx, dtv, acs, st, zx, Dp, yg);
  hipLaunchKernelGGL(k_normquant<DI>, dim3(TOKS), dim3(256), 0, stream, yg, out_norm, q2, rs2);
  hipLaunchKernelGGL(k_gemm_mfma, dim3(TOKS / 128, DM / 128), dim3(256), 0, stream,
                     q2, wq2, rs2, hidden, out, TOKS, DM, DI);
  (void)in_sizes; (void)n_in; (void)out_size; (void)ws_size;
}

// Round 5
// 502.421 us; speedup vs baseline: 3.9505x; 1.1781x over previous
//
#include <hip/hip_runtime.h>
#include <stdint.h>
#include <stddef.h>
#include <math.h>

#define TOKS 4096
#define DM   1024
#define DIP  4384
#define DI   2048
#define CVD  2304
#define NH   32
#define HD   64
#define DST  128
#define NCH  8
#define CHK  256

typedef int v4i  __attribute__((ext_vector_type(4)));
typedef int v16i __attribute__((ext_vector_type(16)));

// ---------------- ws layout (bytes) ----------------
static const size_t OFF_ZX    = 0;                               // float TOKS*DIP
static const size_t OFF_SX    = OFF_ZX + (size_t)TOKS*DIP*4;     // float TOKS*CVD
static const size_t OFF_ST    = OFF_SX + (size_t)TOKS*CVD*4;     // float 2*NCH*NH*HD*DST
static const size_t OFF_YG    = OFF_ST + (size_t)2*NCH*NH*HD*DST*4; // float TOKS*DI
static const size_t OFF_Q1    = OFF_YG + (size_t)TOKS*DI*4;      // i8 TOKS*DM
static const size_t OFF_Q2    = OFF_Q1 + (size_t)TOKS*DM;        // i8 TOKS*DI
static const size_t OFF_WQ1   = OFF_Q2 + (size_t)TOKS*DI;        // i8 DIP*DM
static const size_t OFF_WQ2   = OFF_WQ1 + (size_t)DIP*DM;        // i8 DM*DI
static const size_t OFF_RS1   = OFF_WQ2 + (size_t)DM*DI;         // float TOKS
static const size_t OFF_RS2   = OFF_RS1 + (size_t)TOKS*4;        // float TOKS
static const size_t OFF_DT    = OFF_RS2 + (size_t)TOKS*4;        // float TOKS*NH
static const size_t OFF_ACS   = OFF_DT + (size_t)TOKS*NH*4;      // double 512*CHK
static const size_t OFF_CSUM  = OFF_ACS + (size_t)512*CHK*8;     // double 512
static const size_t OFF_PART  = OFF_CSUM + 512*8;                // double 1024
static const size_t OFF_WSC   = OFF_PART + 1024*8;               // double 2
static const size_t OFF_BTG   = OFF_WSC + 64;                    // float 16*128*256 (B^T per (b,c))

// ---------------- block reduction helpers (blockDim = 256) ----------------
__device__ __forceinline__ double bsumd(double v, double* sb) {
#pragma unroll
  for (int o = 32; o; o >>= 1) v += __shfl_down(v, o);
  int lane = threadIdx.x & 63, w = threadIdx.x >> 6;
  __syncthreads();
  if (lane == 0) sb[w] = v;
  __syncthreads();
  return sb[0] + sb[1] + sb[2] + sb[3];
}
__device__ __forceinline__ double bmaxd(double v, double* sb) {
#pragma unroll
  for (int o = 32; o; o >>= 1) v = fmax(v, __shfl_down(v, o));
  int lane = threadIdx.x & 63, w = threadIdx.x >> 6;
  __syncthreads();
  if (lane == 0) sb[w] = v;
  __syncthreads();
  return fmax(fmax(sb[0], sb[1]), fmax(sb[2], sb[3]));
}

// ---------------- weight scale (mean |w|), fp64 ----------------
__global__ void __launch_bounds__(256) k_absmean(const float* __restrict__ w, int n, double* __restrict__ part) {
  double s = 0.0;
  for (int i = blockIdx.x * 256 + threadIdx.x; i < n; i += 512 * 256) s += (double)fabsf(w[i]);
  __shared__ double sb[4];
  s = bsumd(s, sb);
  if (threadIdx.x == 0) part[blockIdx.x] = s;
}

__global__ void __launch_bounds__(256) k_wscale(const double* __restrict__ part, double* __restrict__ wsc, int n1, int n2) {
  __shared__ double sb[4];
  double s = part[threadIdx.x] + part[threadIdx.x + 256];
  double t1 = bsumd(s, sb);
  __syncthreads();
  s = part[512 + threadIdx.x] + part[512 + threadIdx.x + 256];
  double t2 = bsumd(s, sb);
  if (threadIdx.x == 0) {
    wsc[0] = fmax(t1 / (double)n1, 1e-5);
    wsc[1] = fmax(t2 / (double)n2, 1e-5);
  }
}

__global__ void __launch_bounds__(256) k_tern(const float* __restrict__ w, int n, const double* __restrict__ wsc, int which, int8_t* __restrict__ out) {
  int i = blockIdx.x * 256 + threadIdx.x;
  if (i < n) {
    double sc = wsc[which];
    double q = fmin(fmax(rint((double)w[i] / sc), -1.0), 1.0);
    out[i] = (int8_t)q;
  }
}

// ---------------- rmsnorm + layernorm + activation quant (decisions in fp64) ----------------
template <int D>
__global__ void __launch_bounds__(256) k_normquant(const float* __restrict__ in, const float* __restrict__ w,
                                                   int8_t* __restrict__ q, float* __restrict__ rs) {
  constexpr int E = D / 256;
  int t = blockIdx.x, tid = threadIdx.x;
  const float* row = in + (size_t)t * D;
  __shared__ double sb[4];
  double x[E];
  double ss = 0.0;
#pragma unroll
  for (int i = 0; i < E; i++) { x[i] = (double)row[tid + 256 * i]; ss += x[i] * x[i]; }
  ss = bsumd(ss, sb);
  double rr = 1.0 / sqrt(ss / (double)D + 1e-6);
  double s1 = 0.0;
#pragma unroll
  for (int i = 0; i < E; i++) { x[i] = (double)w[tid + 256 * i] * (x[i] * rr); s1 += x[i]; }
  s1 = bsumd(s1, sb);
  double mu = s1 / (double)D;
  double s2 = 0.0;
#pragma unroll
  for (int i = 0; i < E; i++) { double d = x[i] - mu; s2 += d * d; }
  s2 = bsumd(s2, sb);
  double rv = 1.0 / sqrt(s2 / (double)D + 1e-5);
  double am = 0.0;
#pragma unroll
  for (int i = 0; i < E; i++) { x[i] = (x[i] - mu) * rv; am = fmax(am, fabs(x[i])); }
  am = bmaxd(am, sb);
  am = fmax(am, 1e-5);
  double sc = 127.0 / am;
#pragma unroll
  for (int i = 0; i < E; i++) {
    double qq = fmin(fmax(rint(x[i] * sc), -128.0), 127.0);
    q[(size_t)t * D + tid + 256 * i] = (int8_t)qq;
  }
  if (tid == 0) rs[t] = (float)(am / 127.0);
}

// ---------------- int8 x ternary GEMM via MFMA i8 ----------------
__global__ void __launch_bounds__(256, 3) k_gemm_mfma(const int8_t* __restrict__ A, const int8_t* __restrict__ W,
                                                      const float* __restrict__ rs, const float* __restrict__ addend,
                                                      float* __restrict__ out, int M, int N, int K) {
  __shared__ int8_t Al[128 * 80];
  __shared__ int8_t Bl[128 * 80];
  int m0 = blockIdx.x * 128, n0 = blockIdx.y * 128;
  int t = threadIdx.x;
  int w = t >> 6, lane = t & 63;
  int wm = w >> 1, wn = w & 1;
  int l31 = lane & 31, lh = lane >> 5;

  v16i acc[2][2] = {};

  for (int k0 = 0; k0 < K; k0 += 64) {
    __syncthreads();
#pragma unroll
    for (int it = 0; it < 2; ++it) {
      int c = t + 256 * it;
      int row = c >> 2, kc = (c & 3) * 16;
      int4 av = *(const int4*)(A + (size_t)(m0 + row) * K + k0 + kc);
      *(int4*)(Al + row * 80 + kc) = av;
      int4 bv;
      if (n0 + row < N) bv = *(const int4*)(W + (size_t)(n0 + row) * K + k0 + kc);
      else { bv.x = bv.y = bv.z = bv.w = 0; }
      *(int4*)(Bl + row * 80 + kc) = bv;
    }
    __syncthreads();
#pragma unroll
    for (int ks = 0; ks < 2; ++ks) {
      v4i af[2], bf[2];
#pragma unroll
      for (int tm = 0; tm < 2; ++tm)
        af[tm] = *(const v4i*)(Al + (wm * 64 + tm * 32 + l31) * 80 + ks * 32 + lh * 16);
#pragma unroll
      for (int tn = 0; tn < 2; ++tn)
        bf[tn] = *(const v4i*)(Bl + (wn * 64 + tn * 32 + l31) * 80 + ks * 32 + lh * 16);
#pragma unroll
      for (int tm = 0; tm < 2; ++tm)
#pragma unroll
        for (int tn = 0; tn < 2; ++tn)
          acc[tm][tn] = __builtin_amdgcn_mfma_i32_32x32x32_i8(af[tm], bf[tn], acc[tm][tn], 0, 0, 0);
    }
  }

#pragma unroll
  for (int tm = 0; tm < 2; ++tm)
#pragma unroll
    for (int tn = 0; tn < 2; ++tn) {
      int n = n0 + wn * 64 + tn * 32 + l31;
      if (n < N) {
#pragma unroll
        for (int r = 0; r < 16; ++r) {
          int mrel = (r & 3) + 8 * (r >> 2) + 4 * lh;
          int m = m0 + wm * 64 + tm * 32 + mrel;
          float v = rs[m] * (float)acc[tm][tn][r];
          if (addend) v += addend[(size_t)m * N + n];
          out[(size_t)m * N + n] = v;
        }
      }
    }
}

// ---------------- depthwise causal conv(4) + SiLU ----------------
__global__ void __launch_bounds__(256) k_conv(const float* __restrict__ zx, const float* __restrict__ cw,
                                              const float* __restrict__ cb, float* __restrict__ sx) {
  int c = blockIdx.x * 256 + threadIdx.x;
  int t = blockIdx.y;
  int b = t >> 11, l = t & 2047;
  float acc = cb[c];
#pragma unroll
  for (int k = 0; k < 4; k++) {
    int li = l - 3 + k;
    if (li >= 0) acc = fmaf(zx[(size_t)(b * 2048 + li) * DIP + DI + c], cw[c * 4 + k], acc);
  }
  sx[(size_t)t * CVD + c] = acc / (1.f + expf(-acc));
}

// ---------------- B^T pre-transpose: btg[bc][n][s] = B[bc*256+s][n] ----------------
__global__ void __launch_bounds__(256) k_trb(const float* __restrict__ sx, float* __restrict__ btg) {
  int blk = blockIdx.x;            // bc*4 + stile
  int bc = blk >> 2, s0 = (blk & 3) * 64;
  int t = threadIdx.x;
  __shared__ float lb[64 * 132];
  {
    int s = t >> 2, ng = (t & 3) * 32;
    const float* src = sx + (size_t)(bc * 256 + s0 + s) * CVD + DI + ng;
#pragma unroll
    for (int i = 0; i < 8; i++)
      *(float4*)(&lb[s * 132 + ng + i * 4]) = *(const float4*)(src + i * 4);
  }
  __syncthreads();
  {
    int n = t >> 1, sh = (t & 1) * 32;
    float* dst = btg + (size_t)bc * (128 * 256) + (size_t)n * 256 + s0 + sh;
#pragma unroll
    for (int i = 0; i < 8; i++) {
      float4 v;
      v.x = lb[(sh + i * 4 + 0) * 132 + n];
      v.y = lb[(sh + i * 4 + 1) * 132 + n];
      v.z = lb[(sh + i * 4 + 2) * 132 + n];
      v.w = lb[(sh + i * 4 + 3) * 132 + n];
      *(float4*)(dst + i * 4) = v;
    }
  }
}

// ---------------- dt = softplus(raw + bias) ----------------
__global__ void __launch_bounds__(256) k_dt(const float* __restrict__ zx, const float* __restrict__ dt_bias,
                                            float* __restrict__ dtv) {
  int idx = blockIdx.x * 256 + threadIdx.x;
  int t = idx >> 5, h = idx & 31;
  float x = zx[(size_t)t * DIP + (DI + CVD) + h] + dt_bias[h];
  dtv[idx] = fmaxf(x, 0.f) + log1pf(expf(-fabsf(x)));
}

// ---------------- per-(b,c,h) cumsum of a = dt * (-exp(A_log)), in fp64 ----------------
__global__ void __launch_bounds__(256) k_cumsum(const float* __restrict__ dtv, const float* __restrict__ A_log,
                                                double* __restrict__ acs, double* __restrict__ csum) {
  int bid = blockIdx.x;
  int h = bid & 31, bc = bid >> 5;
  int s = threadIdx.x;
  int tok = bc * 256 + s;
  double negA = -exp((double)A_log[h]);
  double a = (double)dtv[tok * 32 + h] * negA;
  __shared__ double buf[256];
  buf[s] = a;
  __syncthreads();
  for (int o = 1; o < 256; o <<= 1) {
    double add = (s >= o) ? buf[s - o] : 0.0;
    __syncthreads();
    buf[s] += add;
    __syncthreads();
  }
  acs[(size_t)bid * 256 + s] = buf[s];
  if (s == 255) csum[bid] = buf[s];
}

// ---------------- per-chunk states v2: states[p][n] = sum_s du[s,p]*B[s,n] ----------------
__global__ void __launch_bounds__(256, 4) k_states2(const float* __restrict__ sx, const float* __restrict__ dtv,
                                                    const double* __restrict__ acs, const double* __restrict__ csum,
                                                    float* __restrict__ states) {
  int r = blockIdx.x;              // (b*8+c)*32+h
  int h = r & 31, bc = r >> 5;
  int t = threadIdx.x, tx = t & 15, ty = t >> 4;
  __shared__ float du[64 * 68];
  double last = csum[r];
  float acc[4][8] = {};
  for (int s0 = 0; s0 < 256; s0 += 64) {
    __syncthreads();
    {
      int s = t >> 2, pg = (t & 3) * 16;
      int tok = bc * 256 + s0 + s;
      float w = expf((float)(last - acs[(size_t)r * 256 + s0 + s])) * dtv[(size_t)tok * 32 + h];
      const float* xr = sx + (size_t)tok * CVD + h * 64 + pg;
      float* dst = &du[s * 68 + pg];
#pragma unroll
      for (int i = 0; i < 4; i++) {
        float4 v = *(const float4*)(xr + i * 4);
        v.x *= w; v.y *= w; v.z *= w; v.w *= w;
        *(float4*)(dst + i * 4) = v;
      }
    }
    __syncthreads();
#pragma unroll 4
    for (int s = 0; s < 64; s++) {
      int tok = bc * 256 + s0 + s;
      const float* br = sx + (size_t)tok * CVD + DI + ty * 8;
      float4 b0 = *(const float4*)(br);
      float4 b1 = *(const float4*)(br + 4);
      float4 d4 = *(const float4*)(&du[s * 68 + tx * 4]);
      float dd[4] = {d4.x, d4.y, d4.z, d4.w};
      float bv[8] = {b0.x, b0.y, b0.z, b0.w, b1.x, b1.y, b1.z, b1.w};
#pragma unroll
      for (int i = 0; i < 4; i++)
#pragma unroll
        for (int j = 0; j < 8; j++) acc[i][j] = fmaf(dd[i], bv[j], acc[i][j]);
    }
  }
  size_t base = (size_t)r * (HD * DST);
#pragma unroll
  for (int i = 0; i < 4; i++) {
    float4 v0, v1;
    v0.x = acc[i][0]; v0.y = acc[i][1]; v0.z = acc[i][2]; v0.w = acc[i][3];
    v1.x = acc[i][4]; v1.y = acc[i][5]; v1.z = acc[i][6]; v1.w = acc[i][7];
    *(float4*)(states + base + (size_t)(tx * 4 + i) * DST + ty * 8) = v0;
    *(float4*)(states + base + (size_t)(tx * 4 + i) * DST + ty * 8 + 4) = v1;
  }
}

// ---------------- sequential chunk-state recurrence (in-place -> prev_states) ----------------
__global__ void __launch_bounds__(256) k_chunkscan(float* __restrict__ states, const double* __restrict__ csum) {
  int idx = blockIdx.x * 256 + threadIdx.x;
  int n = idx & 127, p = (idx >> 7) & 63, h = (idx >> 13) & 31, b = idx >> 18;
  float Nv = 0.f;
  for (int c = 0; c < 8; c++) {
    int bid = (b * 8 + c) * 32 + h;
    size_t addr = (size_t)bid * (HD * DST) + p * DST + n;
    float s = states[addr];
    states[addr] = Nv;
    Nv = Nv * expf((float)csum[bid]) + s;
  }
}

// ---------------- fused Y (full chunk per block) ----------------
__global__ void __launch_bounds__(256, 3) k_y3(const float* __restrict__ sx, const float* __restrict__ dtv,
                                               const double* __restrict__ acs, const float* __restrict__ prev,
                                               const float* __restrict__ zx, const float* __restrict__ Dp,
                                               const float* __restrict__ btg, float* __restrict__ yg) {
  int r = blockIdx.x;              // (b*8+c)*32+h
  int h = r & 31, bc = r >> 5;
  int t = threadIdx.x, tx = t & 15, ty = t >> 4;

  __shared__ float Bt[128 * 68];   // B^T tile [n][s]; reused as Pt[n][p] for Y_off
  __shared__ float Sl[64 * 68];    // S' tile [l][s] (dt folded)

  float acc[4][4][4] = {};         // [LT][j][jj]
  const double* acsr = acs + (size_t)r * 256;
  const float* btb = btg + (size_t)bc * (128 * 256);

  for (int st = 0; st < 4; ++st) {
    int s0 = st * 64;
    __syncthreads();
    // stage Bt[n][s] from pre-transposed global (all b128)
    {
      int n = t >> 2, sq = (t & 3) * 16;
#pragma unroll
      for (int half = 0; half < 2; ++half) {
        const float* src = btb + (size_t)(n + 64 * half) * 256 + s0 + sq;
        float* dst = &Bt[(n + 64 * half) * 68 + sq];
#pragma unroll
        for (int i = 0; i < 4; i++)
          *(float4*)(dst + i * 4) = *(const float4*)(src + i * 4);
      }
    }
    __syncthreads();
    // s-side constants for this s-tile
    double a_s[4]; float dts[4];
#pragma unroll
    for (int jj = 0; jj < 4; jj++) {
      int s = s0 + tx * 4 + jj;
      a_s[jj] = acsr[s];
      dts[jj] = dtv[(size_t)(bc * 256 + s) * 32 + h];
    }
#pragma unroll
    for (int LT = 0; LT < 4; ++LT) {
      if (LT < st) continue;
      int l0 = LT * 64;
      const float* C0 = sx + (size_t)(bc * 256 + l0 + ty * 4) * CVD + DI + DST;
      // GEMM#1: dotv = C · B^T
      float dotv[4][4] = {};
      for (int nn = 0; nn < 128; nn += 4) {
        float ca[4][4], bb[4][4];
#pragma unroll
        for (int j = 0; j < 4; j++) {
          float4 v = *(const float4*)(C0 + (size_t)j * CVD + nn);
          ca[j][0] = v.x; ca[j][1] = v.y; ca[j][2] = v.z; ca[j][3] = v.w;
        }
#pragma unroll
        for (int q = 0; q < 4; q++) {
          float4 v = *(const float4*)(&Bt[(nn + q) * 68 + tx * 4]);
          bb[q][0] = v.x; bb[q][1] = v.y; bb[q][2] = v.z; bb[q][3] = v.w;
        }
#pragma unroll
        for (int j = 0; j < 4; j++)
#pragma unroll
          for (int q = 0; q < 4; q++)
#pragma unroll
            for (int jj = 0; jj < 4; jj++)
              dotv[j][jj] = fmaf(ca[j][q], bb[q][jj], dotv[j][jj]);
      }
      // decay scale + dt fold + causal mask -> Sl
#pragma unroll
      for (int j = 0; j < 4; j++) {
        double a_l = acsr[l0 + ty * 4 + j];
        float vv[4];
#pragma unroll
        for (int jj = 0; jj < 4; jj++) {
          float v = 0.f;
          if (st < LT || (tx * 4 + jj) <= (ty * 4 + j))
            v = expf((float)(a_l - a_s[jj])) * dotv[j][jj] * dts[jj];
          vv[jj] = v;
        }
        float4 sv; sv.x = vv[0]; sv.y = vv[1]; sv.z = vv[2]; sv.w = vv[3];
        *(float4*)(&Sl[(ty * 4 + j) * 68 + tx * 4]) = sv;
      }
      __syncthreads();
      // GEMM#2: acc[LT] += S' · x   (x rows from global, L1 broadcast)
      const float* xr = sx + (size_t)(bc * 256 + s0) * CVD + h * 64 + tx * 4;
      for (int s4 = 0; s4 < 64; s4 += 4) {
        float sa[4][4], ua[4][4];
#pragma unroll
        for (int q = 0; q < 4; q++) {
          float4 v = *(const float4*)(xr + (size_t)(s4 + q) * CVD);
          ua[q][0] = v.x; ua[q][1] = v.y; ua[q][2] = v.z; ua[q][3] = v.w;
        }
#pragma unroll
        for (int j = 0; j < 4; j++) {
          float4 v = *(const float4*)(&Sl[(ty * 4 + j) * 68 + s4]);
          sa[j][0] = v.x; sa[j][1] = v.y; sa[j][2] = v.z; sa[j][3] = v.w;
        }
#pragma unroll
        for (int j = 0; j < 4; j++)
#pragma unroll
          for (int q = 0; q < 4; q++)
#pragma unroll
            for (int jj = 0; jj < 4; jj++)
              acc[LT][j][jj] = fmaf(sa[j][q], ua[q][jj], acc[LT][j][jj]);
      }
      __syncthreads();
    }
  }

  // Y_off: stage Pt[n][p] = prev[p][n] into Bt region
  __syncthreads();
  {
    int p = t >> 2, ng = (t & 3) * 32;
    const float* pr = prev + (size_t)r * (HD * DST) + p * DST + ng;
#pragma unroll
    for (int i4 = 0; i4 < 8; ++i4) {
      float4 v = *(const float4*)(pr + i4 * 4);
      int nn = ng + i4 * 4;
      Bt[(nn + 0) * 68 + p] = v.x;
      Bt[(nn + 1) * 68 + p] = v.y;
      Bt[(nn + 2) * 68 + p] = v.z;
      Bt[(nn + 3) * 68 + p] = v.w;
    }
  }
  __syncthreads();
#pragma unroll
  for (int LT = 0; LT < 4; ++LT) {
    int l0 = LT * 64;
    const float* C0 = sx + (size_t)(bc * 256 + l0 + ty * 4) * CVD + DI + DST;
    float yo[4][4] = {};
    for (int nn = 0; nn < 128; nn += 4) {
      float ca[4][4], bb[4][4];
#pragma unroll
      for (int j = 0; j < 4; j++) {
        float4 v = *(const float4*)(C0 + (size_t)j * CVD + nn);
        ca[j][0] = v.x; ca[j][1] = v.y; ca[j][2] = v.z; ca[j][3] = v.w;
      }
#pragma unroll
      for (int q = 0; q < 4; q++) {
        float4 v = *(const float4*)(&Bt[(nn + q) * 68 + tx * 4]);
        bb[q][0] = v.x; bb[q][1] = v.y; bb[q][2] = v.z; bb[q][3] = v.w;
      }
#pragma unroll
      for (int j = 0; j < 4; j++)
#pragma unroll
        for (int q = 0; q < 4; q++)
#pragma unroll
          for (int jj = 0; jj < 4; jj++)
            yo[j][jj] = fmaf(ca[j][q], bb[q][jj], yo[j][jj]);
    }
#pragma unroll
    for (int j = 0; j < 4; j++) {
      float el = expf((float)acsr[l0 + ty * 4 + j]);
#pragma unroll
      for (int jj = 0; jj < 4; jj++)
        acc[LT][j][jj] = fmaf(el, yo[j][jj], acc[LT][j][jj]);
    }
  }

  // epilogue: + x*Dp, gate by silu(z)
  float dph = Dp[h];
#pragma unroll
  for (int LT = 0; LT < 4; ++LT) {
#pragma unroll
    for (int j = 0; j < 4; j++) {
      size_t tok = (size_t)(bc * 256 + LT * 64 + ty * 4 + j);
      float4 xv = *(const float4*)(sx + tok * CVD + h * 64 + tx * 4);
      float4 zv = *(const float4*)(zx + tok * DIP + h * 64 + tx * 4);
      float4 o;
      o.x = (acc[LT][j][0] + xv.x * dph) * (zv.x / (1.f + expf(-zv.x)));
      o.y = (acc[LT][j][1] + xv.y * dph) * (zv.y / (1.f + expf(-zv.y)));
      o.z = (acc[LT][j][2] + xv.z * dph) * (zv.z / (1.f + expf(-zv.z)));
      o.w = (acc[LT][j][3] + xv.w * dph) * (zv.w / (1.f + expf(-zv.w)));
      *(float4*)(yg + tok * DI + h * 64 + tx * 4) = o;
    }
  }
}

// ---------------- launch ----------------
extern "C" void kernel_launch(void* const* d_in, const int* in_sizes, int n_in,
                              void* d_out, int out_size, void* d_ws, size_t ws_size,
                              hipStream_t stream) {
  const float* hidden   = (const float*)d_in[0];
  const float* norm_w   = (const float*)d_in[1];
  const float* in_proj  = (const float*)d_in[2];
  const float* conv_w   = (const float*)d_in[3];
  const float* conv_b   = (const float*)d_in[4];
  const float* A_log    = (const float*)d_in[5];
  const float* Dp       = (const float*)d_in[6];
  const float* dt_bias  = (const float*)d_in[7];
  const float* out_norm = (const float*)d_in[8];
  const float* out_proj = (const float*)d_in[9];
  float* out = (float*)d_out;

  char* ws = (char*)d_ws;
  float*  zx    = (float*)(ws + OFF_ZX);
  float*  sx    = (float*)(ws + OFF_SX);
  float*  st    = (float*)(ws + OFF_ST);
  float*  yg    = (float*)(ws + OFF_YG);
  int8_t* q1    = (int8_t*)(ws + OFF_Q1);
  int8_t* q2    = (int8_t*)(ws + OFF_Q2);
  int8_t* wq1   = (int8_t*)(ws + OFF_WQ1);
  int8_t* wq2   = (int8_t*)(ws + OFF_WQ2);
  float*  rs1   = (float*)(ws + OFF_RS1);
  float*  rs2   = (float*)(ws + OFF_RS2);
  float*  dtv   = (float*)(ws + OFF_DT);
  double* acs   = (double*)(ws + OFF_ACS);
  double* csum  = (double*)(ws + OFF_CSUM);
  double* part  = (double*)(ws + OFF_PART);
  double* wsc   = (double*)(ws + OFF_WSC);
  float*  btg   = (float*)(ws + OFF_BTG);

  const int n1 = DIP * DM, n2 = DM * DI;

  hipLaunchKernelGGL(k_absmean, dim3(512), dim3(256), 0, stream, in_proj, n1, part);
  hipLaunchKernelGGL(k_absmean, dim3(512), dim3(256), 0, stream, out_proj, n2, part + 512);
  hipLaunchKernelGGL(k_wscale, dim3(1), dim3(256), 0, stream, part, wsc, n1, n2);
  hipLaunchKernelGGL(k_tern, dim3((n1 + 255) / 256), dim3(256), 0, stream, in_proj, n1, wsc, 0, wq1);
  hipLaunchKernelGGL(k_tern, dim3((n2 + 255) / 256), dim3(256), 0, stream, out_proj, n2, wsc, 1, wq2);
  hipLaunchKernelGGL(k_normquant<DM>, dim3(TOKS), dim3(256), 0, stream, hidden, norm_w, q1, rs1);
  hipLaunchKernelGGL(k_gemm_mfma, dim3(TOKS / 128, (DIP + 127) / 128), dim3(256), 0, stream,
                     q1, wq1, rs1, (const float*)nullptr, zx, TOKS, DIP, DM);
  hipLaunchKernelGGL(k_conv, dim3(CVD / 256, TOKS), dim3(256), 0, stream, zx, conv_w, conv_b, sx);
  hipLaunchKernelGGL(k_trb, dim3(64), dim3(256), 0, stream, sx, btg);
  hipLaunchKernelGGL(k_dt, dim3(TOKS * NH / 256), dim3(256), 0, stream, zx, dt_bias, dtv);
  hipLaunchKernelGGL(k_cumsum, dim3(512), dim3(256), 0, stream, dtv, A_log, acs, csum);
  hipLaunchKernelGGL(k_states2, dim3(512), dim3(256), 0, stream, sx, dtv, acs, csum, st);
  hipLaunchKernelGGL(k_chunkscan, dim3(2 * NH * HD * DST / 256), dim3(256), 0, stream, st, csum);
  hipLaunchKernelGGL(k_y3, dim3(512), dim3(256), 0, stream, sx, dtv, acs, st, zx, Dp, btg, yg);
  hipLaunchKernelGGL(k_normquant<DI>, dim3(TOKS), dim3(256), 0, stream, yg, out_norm, q2, rs2);
  hipLaunchKernelGGL(k_gemm_mfma, dim3(TOKS / 128, DM / 128), dim3(256), 0, stream,
                     q2, wq2, rs2, hidden, out, TOKS, DM, DI);
  (void)in_sizes; (void)n_in; (void)out_size; (void)ws_size;
}

// Round 6
// 363.680 us; speedup vs baseline: 5.4576x; 1.3815x over previous
//
#include <hip/hip_runtime.h>
#include <stdint.h>
#include <stddef.h>
#include <math.h>

#define TOKS 4096
#define DM   1024
#define DIP  4384
#define DI   2048
#define CVD  2304
#define NH   32
#define HD   64
#define DST  128
#define NCH  8
#define CHK  256

typedef int v4i  __attribute__((ext_vector_type(4)));
typedef int v16i __attribute__((ext_vector_type(16)));
typedef short s8v __attribute__((ext_vector_type(8)));
typedef float f16v __attribute__((ext_vector_type(16)));
typedef unsigned short ushort_t;

// ---------------- ws layout (bytes) ----------------
static const size_t OFF_ZX    = 0;                               // float TOKS*DIP
static const size_t OFF_SX    = OFF_ZX + (size_t)TOKS*DIP*4;     // float TOKS*CVD
static const size_t OFF_ST    = OFF_SX + (size_t)TOKS*CVD*4;     // float 2*NCH*NH*HD*DST
static const size_t OFF_YG    = OFF_ST + (size_t)2*NCH*NH*HD*DST*4; // float TOKS*DI
static const size_t OFF_Q1    = OFF_YG + (size_t)TOKS*DI*4;      // i8 TOKS*DM
static const size_t OFF_Q2    = OFF_Q1 + (size_t)TOKS*DM;        // i8 TOKS*DI
static const size_t OFF_WQ1   = OFF_Q2 + (size_t)TOKS*DI;        // i8 DIP*DM
static const size_t OFF_WQ2   = OFF_WQ1 + (size_t)DIP*DM;        // i8 DM*DI
static const size_t OFF_RS1   = OFF_WQ2 + (size_t)DM*DI;         // float TOKS
static const size_t OFF_RS2   = OFF_RS1 + (size_t)TOKS*4;        // float TOKS
static const size_t OFF_DT    = OFF_RS2 + (size_t)TOKS*4;        // float TOKS*NH
static const size_t OFF_ACS   = OFF_DT + (size_t)TOKS*NH*4;      // double 512*CHK
static const size_t OFF_CSUM  = OFF_ACS + (size_t)512*CHK*8;     // double 512
static const size_t OFF_PART  = OFF_CSUM + 512*8;                // double 1024
static const size_t OFF_WSC   = OFF_PART + 1024*8;               // double 2

// ---------------- bf16 split helpers ----------------
__device__ __forceinline__ ushort_t f2bf(float x) {
  union { float f; unsigned int u; } v; v.f = x;
  unsigned int r = v.u + 0x7FFFu + ((v.u >> 16) & 1u);
  return (ushort_t)(r >> 16);
}
__device__ __forceinline__ float bf2f(ushort_t h) {
  union { unsigned int u; float f; } v; v.u = ((unsigned int)h) << 16;
  return v.f;
}
// split 8 floats (two float4) into hi/lo bf16 frags
__device__ __forceinline__ void splitfrag(float4 a, float4 b, s8v& hi, s8v& lo) {
  union { s8v v; ushort_t e[8]; } H, L;
  float f[8] = {a.x, a.y, a.z, a.w, b.x, b.y, b.z, b.w};
#pragma unroll
  for (int i = 0; i < 8; i++) {
    ushort_t h = f2bf(f[i]);
    H.e[i] = h;
    L.e[i] = f2bf(f[i] - bf2f(h));
  }
  hi = H.v; lo = L.v;
}

// ---------------- block reduction helpers (blockDim = 256) ----------------
__device__ __forceinline__ double bsumd(double v, double* sb) {
#pragma unroll
  for (int o = 32; o; o >>= 1) v += __shfl_down(v, o);
  int lane = threadIdx.x & 63, w = threadIdx.x >> 6;
  __syncthreads();
  if (lane == 0) sb[w] = v;
  __syncthreads();
  return sb[0] + sb[1] + sb[2] + sb[3];
}
__device__ __forceinline__ double bmaxd(double v, double* sb) {
#pragma unroll
  for (int o = 32; o; o >>= 1) v = fmax(v, __shfl_down(v, o));
  int lane = threadIdx.x & 63, w = threadIdx.x >> 6;
  __syncthreads();
  if (lane == 0) sb[w] = v;
  __syncthreads();
  return fmax(fmax(sb[0], sb[1]), fmax(sb[2], sb[3]));
}

// ---------------- weight scale (mean |w|), fp64 ----------------
__global__ void __launch_bounds__(256) k_absmean(const float* __restrict__ w, int n, double* __restrict__ part) {
  double s = 0.0;
  for (int i = blockIdx.x * 256 + threadIdx.x; i < n; i += 512 * 256) s += (double)fabsf(w[i]);
  __shared__ double sb[4];
  s = bsumd(s, sb);
  if (threadIdx.x == 0) part[blockIdx.x] = s;
}

__global__ void __launch_bounds__(256) k_wscale(const double* __restrict__ part, double* __restrict__ wsc, int n1, int n2) {
  __shared__ double sb[4];
  double s = part[threadIdx.x] + part[threadIdx.x + 256];
  double t1 = bsumd(s, sb);
  __syncthreads();
  s = part[512 + threadIdx.x] + part[512 + threadIdx.x + 256];
  double t2 = bsumd(s, sb);
  if (threadIdx.x == 0) {
    wsc[0] = fmax(t1 / (double)n1, 1e-5);
    wsc[1] = fmax(t2 / (double)n2, 1e-5);
  }
}

__global__ void __launch_bounds__(256) k_tern(const float* __restrict__ w, int n, const double* __restrict__ wsc, int which, int8_t* __restrict__ out) {
  int i = blockIdx.x * 256 + threadIdx.x;
  if (i < n) {
    double sc = wsc[which];
    double q = fmin(fmax(rint((double)w[i] / sc), -1.0), 1.0);
    out[i] = (int8_t)q;
  }
}

// ---------------- rmsnorm + layernorm + activation quant (decisions in fp64) ----------------
template <int D>
__global__ void __launch_bounds__(256) k_normquant(const float* __restrict__ in, const float* __restrict__ w,
                                                   int8_t* __restrict__ q, float* __restrict__ rs) {
  constexpr int E = D / 256;
  int t = blockIdx.x, tid = threadIdx.x;
  const float* row = in + (size_t)t * D;
  __shared__ double sb[4];
  double x[E];
  double ss = 0.0;
#pragma unroll
  for (int i = 0; i < E; i++) { x[i] = (double)row[tid + 256 * i]; ss += x[i] * x[i]; }
  ss = bsumd(ss, sb);
  double rr = 1.0 / sqrt(ss / (double)D + 1e-6);
  double s1 = 0.0;
#pragma unroll
  for (int i = 0; i < E; i++) { x[i] = (double)w[tid + 256 * i] * (x[i] * rr); s1 += x[i]; }
  s1 = bsumd(s1, sb);
  double mu = s1 / (double)D;
  double s2 = 0.0;
#pragma unroll
  for (int i = 0; i < E; i++) { double d = x[i] - mu; s2 += d * d; }
  s2 = bsumd(s2, sb);
  double rv = 1.0 / sqrt(s2 / (double)D + 1e-5);
  double am = 0.0;
#pragma unroll
  for (int i = 0; i < E; i++) { x[i] = (x[i] - mu) * rv; am = fmax(am, fabs(x[i])); }
  am = bmaxd(am, sb);
  am = fmax(am, 1e-5);
  double sc = 127.0 / am;
#pragma unroll
  for (int i = 0; i < E; i++) {
    double qq = fmin(fmax(rint(x[i] * sc), -128.0), 127.0);
    q[(size_t)t * D + tid + 256 * i] = (int8_t)qq;
  }
  if (tid == 0) rs[t] = (float)(am / 127.0);
}

// ---------------- int8 x ternary GEMM via MFMA i8 ----------------
__global__ void __launch_bounds__(256, 3) k_gemm_mfma(const int8_t* __restrict__ A, const int8_t* __restrict__ W,
                                                      const float* __restrict__ rs, const float* __restrict__ addend,
                                                      float* __restrict__ out, int M, int N, int K) {
  __shared__ int8_t Al[128 * 80];
  __shared__ int8_t Bl[128 * 80];
  int m0 = blockIdx.x * 128, n0 = blockIdx.y * 128;
  int t = threadIdx.x;
  int w = t >> 6, lane = t & 63;
  int wm = w >> 1, wn = w & 1;
  int l31 = lane & 31, lh = lane >> 5;

  v16i acc[2][2] = {};

  for (int k0 = 0; k0 < K; k0 += 64) {
    __syncthreads();
#pragma unroll
    for (int it = 0; it < 2; ++it) {
      int c = t + 256 * it;
      int row = c >> 2, kc = (c & 3) * 16;
      int4 av = *(const int4*)(A + (size_t)(m0 + row) * K + k0 + kc);
      *(int4*)(Al + row * 80 + kc) = av;
      int4 bv;
      if (n0 + row < N) bv = *(const int4*)(W + (size_t)(n0 + row) * K + k0 + kc);
      else { bv.x = bv.y = bv.z = bv.w = 0; }
      *(int4*)(Bl + row * 80 + kc) = bv;
    }
    __syncthreads();
#pragma unroll
    for (int ks = 0; ks < 2; ++ks) {
      v4i af[2], bf[2];
#pragma unroll
      for (int tm = 0; tm < 2; ++tm)
        af[tm] = *(const v4i*)(Al + (wm * 64 + tm * 32 + l31) * 80 + ks * 32 + lh * 16);
#pragma unroll
      for (int tn = 0; tn < 2; ++tn)
        bf[tn] = *(const v4i*)(Bl + (wn * 64 + tn * 32 + l31) * 80 + ks * 32 + lh * 16);
#pragma unroll
      for (int tm = 0; tm < 2; ++tm)
#pragma unroll
        for (int tn = 0; tn < 2; ++tn)
          acc[tm][tn] = __builtin_amdgcn_mfma_i32_32x32x32_i8(af[tm], bf[tn], acc[tm][tn], 0, 0, 0);
    }
  }

#pragma unroll
  for (int tm = 0; tm < 2; ++tm)
#pragma unroll
    for (int tn = 0; tn < 2; ++tn) {
      int n = n0 + wn * 64 + tn * 32 + l31;
      if (n < N) {
#pragma unroll
        for (int r = 0; r < 16; ++r) {
          int mrel = (r & 3) + 8 * (r >> 2) + 4 * lh;
          int m = m0 + wm * 64 + tm * 32 + mrel;
          float v = rs[m] * (float)acc[tm][tn][r];
          if (addend) v += addend[(size_t)m * N + n];
          out[(size_t)m * N + n] = v;
        }
      }
    }
}

// ---------------- depthwise causal conv(4) + SiLU ----------------
__global__ void __launch_bounds__(256) k_conv(const float* __restrict__ zx, const float* __restrict__ cw,
                                              const float* __restrict__ cb, float* __restrict__ sx) {
  int c = blockIdx.x * 256 + threadIdx.x;
  int t = blockIdx.y;
  int b = t >> 11, l = t & 2047;
  float acc = cb[c];
#pragma unroll
  for (int k = 0; k < 4; k++) {
    int li = l - 3 + k;
    if (li >= 0) acc = fmaf(zx[(size_t)(b * 2048 + li) * DIP + DI + c], cw[c * 4 + k], acc);
  }
  sx[(size_t)t * CVD + c] = acc / (1.f + expf(-acc));
}

// ---------------- dt = softplus(raw + bias) ----------------
__global__ void __launch_bounds__(256) k_dt(const float* __restrict__ zx, const float* __restrict__ dt_bias,
                                            float* __restrict__ dtv) {
  int idx = blockIdx.x * 256 + threadIdx.x;
  int t = idx >> 5, h = idx & 31;
  float x = zx[(size_t)t * DIP + (DI + CVD) + h] + dt_bias[h];
  dtv[idx] = fmaxf(x, 0.f) + log1pf(expf(-fabsf(x)));
}

// ---------------- per-(b,c,h) cumsum of a = dt * (-exp(A_log)), in fp64 ----------------
__global__ void __launch_bounds__(256) k_cumsum(const float* __restrict__ dtv, const float* __restrict__ A_log,
                                                double* __restrict__ acs, double* __restrict__ csum) {
  int bid = blockIdx.x;
  int h = bid & 31, bc = bid >> 5;
  int s = threadIdx.x;
  int tok = bc * 256 + s;
  double negA = -exp((double)A_log[h]);
  double a = (double)dtv[tok * 32 + h] * negA;
  __shared__ double buf[256];
  buf[s] = a;
  __syncthreads();
  for (int o = 1; o < 256; o <<= 1) {
    double add = (s >= o) ? buf[s - o] : 0.0;
    __syncthreads();
    buf[s] += add;
    __syncthreads();
  }
  acs[(size_t)bid * 256 + s] = buf[s];
  if (s == 255) csum[bid] = buf[s];
}

// ---------------- per-chunk states v2: states[p][n] = sum_s du[s,p]*B[s,n] ----------------
__global__ void __launch_bounds__(256, 4) k_states2(const float* __restrict__ sx, const float* __restrict__ dtv,
                                                    const double* __restrict__ acs, const double* __restrict__ csum,
                                                    float* __restrict__ states) {
  int r = blockIdx.x;
  int h = r & 31, bc = r >> 5;
  int t = threadIdx.x, tx = t & 15, ty = t >> 4;
  __shared__ float du[64 * 68];
  double last = csum[r];
  float acc[4][8] = {};
  for (int s0 = 0; s0 < 256; s0 += 64) {
    __syncthreads();
    {
      int s = t >> 2, pg = (t & 3) * 16;
      int tok = bc * 256 + s0 + s;
      float w = expf((float)(last - acs[(size_t)r * 256 + s0 + s])) * dtv[(size_t)tok * 32 + h];
      const float* xr = sx + (size_t)tok * CVD + h * 64 + pg;
      float* dst = &du[s * 68 + pg];
#pragma unroll
      for (int i = 0; i < 4; i++) {
        float4 v = *(const float4*)(xr + i * 4);
        v.x *= w; v.y *= w; v.z *= w; v.w *= w;
        *(float4*)(dst + i * 4) = v;
      }
    }
    __syncthreads();
#pragma unroll 4
    for (int s = 0; s < 64; s++) {
      int tok = bc * 256 + s0 + s;
      const float* br = sx + (size_t)tok * CVD + DI + ty * 8;
      float4 b0 = *(const float4*)(br);
      float4 b1 = *(const float4*)(br + 4);
      float4 d4 = *(const float4*)(&du[s * 68 + tx * 4]);
      float dd[4] = {d4.x, d4.y, d4.z, d4.w};
      float bv[8] = {b0.x, b0.y, b0.z, b0.w, b1.x, b1.y, b1.z, b1.w};
#pragma unroll
      for (int i = 0; i < 4; i++)
#pragma unroll
        for (int j = 0; j < 8; j++) acc[i][j] = fmaf(dd[i], bv[j], acc[i][j]);
    }
  }
  size_t base = (size_t)r * (HD * DST);
#pragma unroll
  for (int i = 0; i < 4; i++) {
    float4 v0, v1;
    v0.x = acc[i][0]; v0.y = acc[i][1]; v0.z = acc[i][2]; v0.w = acc[i][3];
    v1.x = acc[i][4]; v1.y = acc[i][5]; v1.z = acc[i][6]; v1.w = acc[i][7];
    *(float4*)(states + base + (size_t)(tx * 4 + i) * DST + ty * 8) = v0;
    *(float4*)(states + base + (size_t)(tx * 4 + i) * DST + ty * 8 + 4) = v1;
  }
}

// ---------------- sequential chunk-state recurrence (in-place -> prev_states) ----------------
__global__ void __launch_bounds__(256) k_chunkscan(float* __restrict__ states, const double* __restrict__ csum) {
  int idx = blockIdx.x * 256 + threadIdx.x;
  int n = idx & 127, p = (idx >> 7) & 63, h = (idx >> 13) & 31, b = idx >> 18;
  float Nv = 0.f;
  for (int c = 0; c < 8; c++) {
    int bid = (b * 8 + c) * 32 + h;
    size_t addr = (size_t)bid * (HD * DST) + p * DST + n;
    float s = states[addr];
    states[addr] = Nv;
    Nv = Nv * expf((float)csum[bid]) + s;
  }
}

// ---------------- fused Y via split-bf16 MFMA ----------------
// block = (b,c,h, l-half): 1024 blocks, 4 waves, wave owns 32 l-rows.
__global__ void __launch_bounds__(256, 2) k_y4(const float* __restrict__ sx, const float* __restrict__ dtv,
                                               const double* __restrict__ acs, const float* __restrict__ prev,
                                               const float* __restrict__ zx, const float* __restrict__ Dp,
                                               float* __restrict__ yg) {
  int bid = blockIdx.x;
  int r = bid >> 1, half = bid & 1;      // r = (b*8+c)*32+h
  int h = r & 31, bc = r >> 5;
  int t = threadIdx.x;
  int w = t >> 6, lane = t & 63;
  int l31 = lane & 31, lhf = lane >> 5;
  int lw = half * 128 + w * 32;          // wave's l-tile start within chunk

  __shared__ ushort_t Bh[32 * 136], Blo[32 * 136];   // B tile bf16 [s][n]
  __shared__ ushort_t Uh[64 * 40],  Ulo[64 * 40];    // u^T tile bf16 [p][s]
  __shared__ float    Sll[4][32 * 36];               // per-wave S' fp32 [l][s]
  __shared__ double   acs_s[256];

  // stage acs
  acs_s[t] = acs[(size_t)r * 256 + t];
  __syncthreads();

  // C fragments in registers (reused by S-phase every subtile and by Y_off)
  s8v Ch[8], Cl[8];
  {
    int tokl = bc * 256 + lw + l31;
    const float* Crow = sx + (size_t)tokl * CVD + DI + DST;
#pragma unroll
    for (int ks = 0; ks < 8; ++ks) {
      float4 a = *(const float4*)(Crow + ks * 16 + lhf * 8);
      float4 b = *(const float4*)(Crow + ks * 16 + lhf * 8 + 4);
      splitfrag(a, b, Ch[ks], Cl[ks]);
    }
  }

  // ---- Y_off FIRST: Yacc = C · prev^T, then scale rows by exp(acs_l) ----
  f16v Yacc[2] = {};
#pragma unroll
  for (int pt = 0; pt < 2; ++pt) {
    const float* pr = prev + (size_t)r * (HD * DST) + (size_t)(pt * 32 + l31) * DST;
#pragma unroll
    for (int ks = 0; ks < 8; ++ks) {
      float4 a = *(const float4*)(pr + ks * 16 + lhf * 8);
      float4 b = *(const float4*)(pr + ks * 16 + lhf * 8 + 4);
      s8v ph, pl;
      splitfrag(a, b, ph, pl);
      Yacc[pt] = __builtin_amdgcn_mfma_f32_32x32x16_bf16(Ch[ks], ph, Yacc[pt], 0, 0, 0);
      Yacc[pt] = __builtin_amdgcn_mfma_f32_32x32x16_bf16(Ch[ks], pl, Yacc[pt], 0, 0, 0);
      Yacc[pt] = __builtin_amdgcn_mfma_f32_32x32x16_bf16(Cl[ks], ph, Yacc[pt], 0, 0, 0);
    }
  }
  // rescale by exp(acs_l) (acs <= 0 so no overflow)
#pragma unroll
  for (int rr = 0; rr < 16; ++rr) {
    int lrow = (rr & 3) + 8 * (rr >> 2) + 4 * lhf;
    float el = expf((float)acs_s[lw + lrow]);
    Yacc[0][rr] *= el;
    Yacc[1][rr] *= el;
  }

  // ---- main loop over 32-wide s subtiles ----
  int nsub = half * 4 + 4;
  for (int st = 0; st < nsub; ++st) {
    int s0 = st * 32;
    __syncthreads();
    // stage B tile: [32 s][128 n] -> bf16 hi/lo
    {
      int srow = t >> 3, n0 = (t & 7) * 16;
      const float* src = sx + (size_t)(bc * 256 + s0 + srow) * CVD + DI + n0;
      float f[16];
#pragma unroll
      for (int i = 0; i < 4; i++) {
        float4 v = *(const float4*)(src + i * 4);
        f[i * 4 + 0] = v.x; f[i * 4 + 1] = v.y; f[i * 4 + 2] = v.z; f[i * 4 + 3] = v.w;
      }
#pragma unroll
      for (int j = 0; j < 8; j++) {
        ushort_t h0 = f2bf(f[2 * j]), h1 = f2bf(f[2 * j + 1]);
        ushort_t l0 = f2bf(f[2 * j] - bf2f(h0)), l1 = f2bf(f[2 * j + 1] - bf2f(h1));
        *(unsigned int*)(&Bh[srow * 136 + n0 + 2 * j])  = (unsigned int)h0 | ((unsigned int)h1 << 16);
        *(unsigned int*)(&Blo[srow * 136 + n0 + 2 * j]) = (unsigned int)l0 | ((unsigned int)l1 << 16);
      }
    }
    // stage u^T tile: [64 p][32 s] from x rows (transposed scalar writes)
    {
      int srow = t >> 3, p0 = (t & 7) * 8;
      const float* xr = sx + (size_t)(bc * 256 + s0 + srow) * CVD + h * 64 + p0;
      float4 v0 = *(const float4*)(xr);
      float4 v1 = *(const float4*)(xr + 4);
      float f[8] = {v0.x, v0.y, v0.z, v0.w, v1.x, v1.y, v1.z, v1.w};
#pragma unroll
      for (int j = 0; j < 8; j++) {
        ushort_t hh = f2bf(f[j]);
        Uh[(p0 + j) * 40 + srow] = hh;
        Ulo[(p0 + j) * 40 + srow] = f2bf(f[j] - bf2f(hh));
      }
    }
    __syncthreads();

    if (s0 <= lw + 31) {
      // S-phase: Sacc[l][s] = sum_n C[l][n] * B[s][n]
      f16v Sacc = {};
#pragma unroll
      for (int ks = 0; ks < 8; ++ks) {
        s8v bh = *(const s8v*)(&Bh[l31 * 136 + ks * 16 + lhf * 8]);
        s8v bl = *(const s8v*)(&Blo[l31 * 136 + ks * 16 + lhf * 8]);
        Sacc = __builtin_amdgcn_mfma_f32_32x32x16_bf16(Ch[ks], bh, Sacc, 0, 0, 0);
        Sacc = __builtin_amdgcn_mfma_f32_32x32x16_bf16(Ch[ks], bl, Sacc, 0, 0, 0);
        Sacc = __builtin_amdgcn_mfma_f32_32x32x16_bf16(Cl[ks], bh, Sacc, 0, 0, 0);
      }
      // epilogue: decay * mask * dt -> private LDS fp32
      int sg = s0 + l31;
      float dts = dtv[(size_t)(bc * 256 + sg) * 32 + h];
      double a_s = acs_s[sg];
#pragma unroll
      for (int rr = 0; rr < 16; ++rr) {
        int lrow = (rr & 3) + 8 * (rr >> 2) + 4 * lhf;
        int lg = lw + lrow;
        float v = 0.f;
        if (sg <= lg) v = expf((float)(acs_s[lg] - a_s)) * Sacc[rr] * dts;
        Sll[w][lrow * 36 + l31] = v;
      }
      // G2: Yacc += S' * u   (A from private LDS fp32, split on the fly)
#pragma unroll
      for (int ks2 = 0; ks2 < 2; ++ks2) {
        float4 a = *(const float4*)(&Sll[w][l31 * 36 + ks2 * 16 + lhf * 8]);
        float4 b = *(const float4*)(&Sll[w][l31 * 36 + ks2 * 16 + lhf * 8 + 4]);
        s8v sah, sal;
        splitfrag(a, b, sah, sal);
#pragma unroll
        for (int pt = 0; pt < 2; ++pt) {
          s8v uh = *(const s8v*)(&Uh[(pt * 32 + l31) * 40 + ks2 * 16 + lhf * 8]);
          s8v ul = *(const s8v*)(&Ulo[(pt * 32 + l31) * 40 + ks2 * 16 + lhf * 8]);
          Yacc[pt] = __builtin_amdgcn_mfma_f32_32x32x16_bf16(sah, uh, Yacc[pt], 0, 0, 0);
          Yacc[pt] = __builtin_amdgcn_mfma_f32_32x32x16_bf16(sah, ul, Yacc[pt], 0, 0, 0);
          Yacc[pt] = __builtin_amdgcn_mfma_f32_32x32x16_bf16(sal, uh, Yacc[pt], 0, 0, 0);
        }
      }
    }
  }

  // ---- epilogue: + x*Dp, gate silu(z), store ----
  float dph = Dp[h];
#pragma unroll
  for (int pt = 0; pt < 2; ++pt) {
    int p = pt * 32 + l31;
#pragma unroll
    for (int rr = 0; rr < 16; ++rr) {
      int lrow = (rr & 3) + 8 * (rr >> 2) + 4 * lhf;
      size_t tok = (size_t)(bc * 256 + lw + lrow);
      float xv = sx[tok * CVD + h * 64 + p];
      float zv = zx[tok * DIP + h * 64 + p];
      float y = (Yacc[pt][rr] + xv * dph) * (zv / (1.f + expf(-zv)));
      yg[tok * DI + h * 64 + p] = y;
    }
  }
}

// ---------------- launch ----------------
extern "C" void kernel_launch(void* const* d_in, const int* in_sizes, int n_in,
                              void* d_out, int out_size, void* d_ws, size_t ws_size,
                              hipStream_t stream) {
  const float* hidden   = (const float*)d_in[0];
  const float* norm_w   = (const float*)d_in[1];
  const float* in_proj  = (const float*)d_in[2];
  const float* conv_w   = (const float*)d_in[3];
  const float* conv_b   = (const float*)d_in[4];
  const float* A_log    = (const float*)d_in[5];
  const float* Dp       = (const float*)d_in[6];
  const float* dt_bias  = (const float*)d_in[7];
  const float* out_norm = (const float*)d_in[8];
  const float* out_proj = (const float*)d_in[9];
  float* out = (float*)d_out;

  char* ws = (char*)d_ws;
  float*  zx    = (float*)(ws + OFF_ZX);
  float*  sx    = (float*)(ws + OFF_SX);
  float*  st    = (float*)(ws + OFF_ST);
  float*  yg    = (float*)(ws + OFF_YG);
  int8_t* q1    = (int8_t*)(ws + OFF_Q1);
  int8_t* q2    = (int8_t*)(ws + OFF_Q2);
  int8_t* wq1   = (int8_t*)(ws + OFF_WQ1);
  int8_t* wq2   = (int8_t*)(ws + OFF_WQ2);
  float*  rs1   = (float*)(ws + OFF_RS1);
  float*  rs2   = (float*)(ws + OFF_RS2);
  float*  dtv   = (float*)(ws + OFF_DT);
  double* acs   = (double*)(ws + OFF_ACS);
  double* csum  = (double*)(ws + OFF_CSUM);
  double* part  = (double*)(ws + OFF_PART);
  double* wsc   = (double*)(ws + OFF_WSC);

  const int n1 = DIP * DM, n2 = DM * DI;

  hipLaunchKernelGGL(k_absmean, dim3(512), dim3(256), 0, stream, in_proj, n1, part);
  hipLaunchKernelGGL(k_absmean, dim3(512), dim3(256), 0, stream, out_proj, n2, part + 512);
  hipLaunchKernelGGL(k_wscale, dim3(1), dim3(256), 0, stream, part, wsc, n1, n2);
  hipLaunchKernelGGL(k_tern, dim3((n1 + 255) / 256), dim3(256), 0, stream, in_proj, n1, wsc, 0, wq1);
  hipLaunchKernelGGL(k_tern, dim3((n2 + 255) / 256), dim3(256), 0, stream, out_proj, n2, wsc, 1, wq2);
  hipLaunchKernelGGL(k_normquant<DM>, dim3(TOKS), dim3(256), 0, stream, hidden, norm_w, q1, rs1);
  hipLaunchKernelGGL(k_gemm_mfma, dim3(TOKS / 128, (DIP + 127) / 128), dim3(256), 0, stream,
                     q1, wq1, rs1, (const float*)nullptr, zx, TOKS, DIP, DM);
  hipLaunchKernelGGL(k_conv, dim3(CVD / 256, TOKS), dim3(256), 0, stream, zx, conv_w, conv_b, sx);
  hipLaunchKernelGGL(k_dt, dim3(TOKS * NH / 256), dim3(256), 0, stream, zx, dt_bias, dtv);
  hipLaunchKernelGGL(k_cumsum, dim3(512), dim3(256), 0, stream, dtv, A_log, acs, csum);
  hipLaunchKernelGGL(k_states2, dim3(512), dim3(256), 0, stream, sx, dtv, acs, csum, st);
  hipLaunchKernelGGL(k_chunkscan, dim3(2 * NH * HD * DST / 256), dim3(256), 0, stream, st, csum);
  hipLaunchKernelGGL(k_y4, dim3(1024), dim3(256), 0, stream, sx, dtv, acs, st, zx, Dp, yg);
  hipLaunchKernelGGL(k_normquant<DI>, dim3(TOKS), dim3(256), 0, stream, yg, out_norm, q2, rs2);
  hipLaunchKernelGGL(k_gemm_mfma, dim3(TOKS / 128, DM / 128), dim3(256), 0, stream,
                     q2, wq2, rs2, hidden, out, TOKS, DM, DI);
  (void)in_sizes; (void)n_in; (void)out_size; (void)ws_size;
}

// Round 8
// 360.961 us; speedup vs baseline: 5.4987x; 1.0075x over previous
//
#include <hip/hip_runtime.h>
#include <stdint.h>
#include <stddef.h>
#include <math.h>

#define TOKS 4096
#define DM   1024
#define DIP  4384
#define DI   2048
#define CVD  2304
#define NH   32
#define HD   64
#define DST  128
#define NCH  8
#define CHK  256

typedef int v4i  __attribute__((ext_vector_type(4)));
typedef int v16i __attribute__((ext_vector_type(16)));
typedef short s8v __attribute__((ext_vector_type(8)));
typedef float f16v __attribute__((ext_vector_type(16)));
typedef unsigned short ushort_t;

// ---------------- ws layout (bytes) ----------------
static const size_t OFF_ZX    = 0;                               // float TOKS*DIP
static const size_t OFF_SX    = OFF_ZX + (size_t)TOKS*DIP*4;     // float TOKS*CVD
static const size_t OFF_ST    = OFF_SX + (size_t)TOKS*CVD*4;     // float 2*NCH*NH*HD*DST
static const size_t OFF_YG    = OFF_ST + (size_t)2*NCH*NH*HD*DST*4; // float TOKS*DI
static const size_t OFF_Q1    = OFF_YG + (size_t)TOKS*DI*4;      // i8 TOKS*DM
static const size_t OFF_Q2    = OFF_Q1 + (size_t)TOKS*DM;        // i8 TOKS*DI
static const size_t OFF_WQ1   = OFF_Q2 + (size_t)TOKS*DI;        // i8 DIP*DM
static const size_t OFF_WQ2   = OFF_WQ1 + (size_t)DIP*DM;        // i8 DM*DI
static const size_t OFF_RS1   = OFF_WQ2 + (size_t)DM*DI;         // float TOKS
static const size_t OFF_RS2   = OFF_RS1 + (size_t)TOKS*4;        // float TOKS
static const size_t OFF_DT    = OFF_RS2 + (size_t)TOKS*4;        // float TOKS*NH
static const size_t OFF_ACS   = OFF_DT + (size_t)TOKS*NH*4;      // double 512*CHK
static const size_t OFF_CSUM  = OFF_ACS + (size_t)512*CHK*8;     // double 512
static const size_t OFF_PART  = OFF_CSUM + 512*8;                // double 1024
static const size_t OFF_WSC   = OFF_PART + 1024*8;               // double 2
static const size_t OFF_BH    = OFF_WSC + 64;                    // ushort TOKS*128
static const size_t OFF_BL    = OFF_BH + (size_t)TOKS*128*2;     // ushort TOKS*128

// ---------------- bf16 split helpers ----------------
__device__ __forceinline__ ushort_t f2bf(float x) {
  union { float f; unsigned int u; } v; v.f = x;
  unsigned int r = v.u + 0x7FFFu + ((v.u >> 16) & 1u);
  return (ushort_t)(r >> 16);
}
__device__ __forceinline__ float bf2f(ushort_t h) {
  union { unsigned int u; float f; } v; v.u = ((unsigned int)h) << 16;
  return v.f;
}
__device__ __forceinline__ void splitfrag(float4 a, float4 b, s8v& hi, s8v& lo) {
  union { s8v v; ushort_t e[8]; } H, L;
  float f[8] = {a.x, a.y, a.z, a.w, b.x, b.y, b.z, b.w};
#pragma unroll
  for (int i = 0; i < 8; i++) {
    ushort_t h = f2bf(f[i]);
    H.e[i] = h;
    L.e[i] = f2bf(f[i] - bf2f(h));
  }
  hi = H.v; lo = L.v;
}

// ---------------- block reduction helpers (blockDim = 256) ----------------
__device__ __forceinline__ double bsumd(double v, double* sb) {
#pragma unroll
  for (int o = 32; o; o >>= 1) v += __shfl_down(v, o);
  int lane = threadIdx.x & 63, w = threadIdx.x >> 6;
  __syncthreads();
  if (lane == 0) sb[w] = v;
  __syncthreads();
  return sb[0] + sb[1] + sb[2] + sb[3];
}
__device__ __forceinline__ double bmaxd(double v, double* sb) {
#pragma unroll
  for (int o = 32; o; o >>= 1) v = fmax(v, __shfl_down(v, o));
  int lane = threadIdx.x & 63, w = threadIdx.x >> 6;
  __syncthreads();
  if (lane == 0) sb[w] = v;
  __syncthreads();
  return fmax(fmax(sb[0], sb[1]), fmax(sb[2], sb[3]));
}

// ---------------- weight scale (mean |w|), fp64 ----------------
__global__ void __launch_bounds__(256) k_absmean(const float* __restrict__ w, int n, double* __restrict__ part) {
  double s = 0.0;
  for (int i = blockIdx.x * 256 + threadIdx.x; i < n; i += 512 * 256) s += (double)fabsf(w[i]);
  __shared__ double sb[4];
  s = bsumd(s, sb);
  if (threadIdx.x == 0) part[blockIdx.x] = s;
}

__global__ void __launch_bounds__(256) k_wscale(const double* __restrict__ part, double* __restrict__ wsc, int n1, int n2) {
  __shared__ double sb[4];
  double s = part[threadIdx.x] + part[threadIdx.x + 256];
  double t1 = bsumd(s, sb);
  __syncthreads();
  s = part[512 + threadIdx.x] + part[512 + threadIdx.x + 256];
  double t2 = bsumd(s, sb);
  if (threadIdx.x == 0) {
    wsc[0] = fmax(t1 / (double)n1, 1e-5);
    wsc[1] = fmax(t2 / (double)n2, 1e-5);
  }
}

__global__ void __launch_bounds__(256) k_tern(const float* __restrict__ w, int n, const double* __restrict__ wsc, int which, int8_t* __restrict__ out) {
  int i = blockIdx.x * 256 + threadIdx.x;
  if (i < n) {
    double sc = wsc[which];
    double q = fmin(fmax(rint((double)w[i] / sc), -1.0), 1.0);
    out[i] = (int8_t)q;
  }
}

// ---------------- rmsnorm + layernorm + activation quant (decisions in fp64) ----------------
template <int D>
__global__ void __launch_bounds__(256) k_normquant(const float* __restrict__ in, const float* __restrict__ w,
                                                   int8_t* __restrict__ q, float* __restrict__ rs) {
  constexpr int E = D / 256;
  int t = blockIdx.x, tid = threadIdx.x;
  const float* row = in + (size_t)t * D;
  __shared__ double sb[4];
  double x[E];
  double ss = 0.0;
#pragma unroll
  for (int i = 0; i < E; i++) { x[i] = (double)row[tid + 256 * i]; ss += x[i] * x[i]; }
  ss = bsumd(ss, sb);
  double rr = 1.0 / sqrt(ss / (double)D + 1e-6);
  double s1 = 0.0;
#pragma unroll
  for (int i = 0; i < E; i++) { x[i] = (double)w[tid + 256 * i] * (x[i] * rr); s1 += x[i]; }
  s1 = bsumd(s1, sb);
  double mu = s1 / (double)D;
  double s2 = 0.0;
#pragma unroll
  for (int i = 0; i < E; i++) { double d = x[i] - mu; s2 += d * d; }
  s2 = bsumd(s2, sb);
  double rv = 1.0 / sqrt(s2 / (double)D + 1e-5);
  double am = 0.0;
#pragma unroll
  for (int i = 0; i < E; i++) { x[i] = (x[i] - mu) * rv; am = fmax(am, fabs(x[i])); }
  am = bmaxd(am, sb);
  am = fmax(am, 1e-5);
  double sc = 127.0 / am;
#pragma unroll
  for (int i = 0; i < E; i++) {
    double qq = fmin(fmax(rint(x[i] * sc), -128.0), 127.0);
    q[(size_t)t * D + tid + 256 * i] = (int8_t)qq;
  }
  if (tid == 0) rs[t] = (float)(am / 127.0);
}

// ---------------- int8 x ternary GEMM via MFMA i8 ----------------
__global__ void __launch_bounds__(256, 3) k_gemm_mfma(const int8_t* __restrict__ A, const int8_t* __restrict__ W,
                                                      const float* __restrict__ rs, const float* __restrict__ addend,
                                                      float* __restrict__ out, int M, int N, int K) {
  __shared__ int8_t Al[128 * 80];
  __shared__ int8_t Bl[128 * 80];
  int m0 = blockIdx.x * 128, n0 = blockIdx.y * 128;
  int t = threadIdx.x;
  int w = t >> 6, lane = t & 63;
  int wm = w >> 1, wn = w & 1;
  int l31 = lane & 31, lh = lane >> 5;

  v16i acc[2][2] = {};

  for (int k0 = 0; k0 < K; k0 += 64) {
    __syncthreads();
#pragma unroll
    for (int it = 0; it < 2; ++it) {
      int c = t + 256 * it;
      int row = c >> 2, kc = (c & 3) * 16;
      int4 av = *(const int4*)(A + (size_t)(m0 + row) * K + k0 + kc);
      *(int4*)(Al + row * 80 + kc) = av;
      int4 bv;
      if (n0 + row < N) bv = *(const int4*)(W + (size_t)(n0 + row) * K + k0 + kc);
      else { bv.x = bv.y = bv.z = bv.w = 0; }
      *(int4*)(Bl + row * 80 + kc) = bv;
    }
    __syncthreads();
#pragma unroll
    for (int ks = 0; ks < 2; ++ks) {
      v4i af[2], bf[2];
#pragma unroll
      for (int tm = 0; tm < 2; ++tm)
        af[tm] = *(const v4i*)(Al + (wm * 64 + tm * 32 + l31) * 80 + ks * 32 + lh * 16);
#pragma unroll
      for (int tn = 0; tn < 2; ++tn)
        bf[tn] = *(const v4i*)(Bl + (wn * 64 + tn * 32 + l31) * 80 + ks * 32 + lh * 16);
#pragma unroll
      for (int tm = 0; tm < 2; ++tm)
#pragma unroll
        for (int tn = 0; tn < 2; ++tn)
          acc[tm][tn] = __builtin_amdgcn_mfma_i32_32x32x32_i8(af[tm], bf[tn], acc[tm][tn], 0, 0, 0);
    }
  }

#pragma unroll
  for (int tm = 0; tm < 2; ++tm)
#pragma unroll
    for (int tn = 0; tn < 2; ++tn) {
      int n = n0 + wn * 64 + tn * 32 + l31;
      if (n < N) {
#pragma unroll
        for (int r = 0; r < 16; ++r) {
          int mrel = (r & 3) + 8 * (r >> 2) + 4 * lh;
          int m = m0 + wm * 64 + tm * 32 + mrel;
          float v = rs[m] * (float)acc[tm][tn][r];
          if (addend) v += addend[(size_t)m * N + n];
          out[(size_t)m * N + n] = v;
        }
      }
    }
}

// ---------------- depthwise causal conv(4) + SiLU ----------------
__global__ void __launch_bounds__(256) k_conv(const float* __restrict__ zx, const float* __restrict__ cw,
                                              const float* __restrict__ cb, float* __restrict__ sx) {
  int c = blockIdx.x * 256 + threadIdx.x;
  int t = blockIdx.y;
  int b = t >> 11, l = t & 2047;
  float acc = cb[c];
#pragma unroll
  for (int k = 0; k < 4; k++) {
    int li = l - 3 + k;
    if (li >= 0) acc = fmaf(zx[(size_t)(b * 2048 + li) * DIP + DI + c], cw[c * 4 + k], acc);
  }
  sx[(size_t)t * CVD + c] = acc / (1.f + expf(-acc));
}

// ---------------- global B bf16 hi/lo split ----------------
__global__ void __launch_bounds__(256) k_splitb(const float* __restrict__ sx, ushort_t* __restrict__ bh,
                                                ushort_t* __restrict__ bl) {
  int idx = blockIdx.x * 256 + threadIdx.x;   // TOKS*32
  int tok = idx >> 5, c4 = (idx & 31) * 4;
  float4 v = *(const float4*)(sx + (size_t)tok * CVD + DI + c4);
  float f[4] = {v.x, v.y, v.z, v.w};
  ushort_t hh[4], ll[4];
#pragma unroll
  for (int j = 0; j < 4; j++) { hh[j] = f2bf(f[j]); ll[j] = f2bf(f[j] - bf2f(hh[j])); }
  uint2 hv, lv;
  hv.x = (unsigned)hh[0] | ((unsigned)hh[1] << 16); hv.y = (unsigned)hh[2] | ((unsigned)hh[3] << 16);
  lv.x = (unsigned)ll[0] | ((unsigned)ll[1] << 16); lv.y = (unsigned)ll[2] | ((unsigned)ll[3] << 16);
  *(uint2*)(bh + (size_t)tok * 128 + c4) = hv;
  *(uint2*)(bl + (size_t)tok * 128 + c4) = lv;
}

// ---------------- dt = softplus(raw + bias) ----------------
__global__ void __launch_bounds__(256) k_dt(const float* __restrict__ zx, const float* __restrict__ dt_bias,
                                            float* __restrict__ dtv) {
  int idx = blockIdx.x * 256 + threadIdx.x;
  int t = idx >> 5, h = idx & 31;
  float x = zx[(size_t)t * DIP + (DI + CVD) + h] + dt_bias[h];
  dtv[idx] = fmaxf(x, 0.f) + log1pf(expf(-fabsf(x)));
}

// ---------------- per-(b,c,h) cumsum of a = dt * (-exp(A_log)), in fp64 ----------------
__global__ void __launch_bounds__(256) k_cumsum(const float* __restrict__ dtv, const float* __restrict__ A_log,
                                                double* __restrict__ acs, double* __restrict__ csum) {
  int bid = blockIdx.x;
  int h = bid & 31, bc = bid >> 5;
  int s = threadIdx.x;
  int tok = bc * 256 + s;
  double negA = -exp((double)A_log[h]);
  double a = (double)dtv[tok * 32 + h] * negA;
  __shared__ double buf[256];
  buf[s] = a;
  __syncthreads();
  for (int o = 1; o < 256; o <<= 1) {
    double add = (s >= o) ? buf[s - o] : 0.0;
    __syncthreads();
    buf[s] += add;
    __syncthreads();
  }
  acs[(size_t)bid * 256 + s] = buf[s];
  if (s == 255) csum[bid] = buf[s];
}

// ---------------- per-chunk states v2: states[p][n] = sum_s du[s,p]*B[s,n] ----------------
__global__ void __launch_bounds__(256, 4) k_states2(const float* __restrict__ sx, const float* __restrict__ dtv,
                                                    const double* __restrict__ acs, const double* __restrict__ csum,
                                                    float* __restrict__ states) {
  int r = blockIdx.x;
  int h = r & 31, bc = r >> 5;
  int t = threadIdx.x, tx = t & 15, ty = t >> 4;
  __shared__ float du[64 * 68];
  double last = csum[r];
  float acc[4][8] = {};
  for (int s0 = 0; s0 < 256; s0 += 64) {
    __syncthreads();
    {
      int s = t >> 2, pg = (t & 3) * 16;
      int tok = bc * 256 + s0 + s;
      float w = expf((float)(last - acs[(size_t)r * 256 + s0 + s])) * dtv[(size_t)tok * 32 + h];
      const float* xr = sx + (size_t)tok * CVD + h * 64 + pg;
      float* dst = &du[s * 68 + pg];
#pragma unroll
      for (int i = 0; i < 4; i++) {
        float4 v = *(const float4*)(xr + i * 4);
        v.x *= w; v.y *= w; v.z *= w; v.w *= w;
        *(float4*)(dst + i * 4) = v;
      }
    }
    __syncthreads();
#pragma unroll 4
    for (int s = 0; s < 64; s++) {
      int tok = bc * 256 + s0 + s;
      const float* br = sx + (size_t)tok * CVD + DI + ty * 8;
      float4 b0 = *(const float4*)(br);
      float4 b1 = *(const float4*)(br + 4);
      float4 d4 = *(const float4*)(&du[s * 68 + tx * 4]);
      float dd[4] = {d4.x, d4.y, d4.z, d4.w};
      float bv[8] = {b0.x, b0.y, b0.z, b0.w, b1.x, b1.y, b1.z, b1.w};
#pragma unroll
      for (int i = 0; i < 4; i++)
#pragma unroll
        for (int j = 0; j < 8; j++) acc[i][j] = fmaf(dd[i], bv[j], acc[i][j]);
    }
  }
  size_t base = (size_t)r * (HD * DST);
#pragma unroll
  for (int i = 0; i < 4; i++) {
    float4 v0, v1;
    v0.x = acc[i][0]; v0.y = acc[i][1]; v0.z = acc[i][2]; v0.w = acc[i][3];
    v1.x = acc[i][4]; v1.y = acc[i][5]; v1.z = acc[i][6]; v1.w = acc[i][7];
    *(float4*)(states + base + (size_t)(tx * 4 + i) * DST + ty * 8) = v0;
    *(float4*)(states + base + (size_t)(tx * 4 + i) * DST + ty * 8 + 4) = v1;
  }
}

// ---------------- sequential chunk-state recurrence (in-place -> prev_states) ----------------
__global__ void __launch_bounds__(256) k_chunkscan(float* __restrict__ states, const double* __restrict__ csum) {
  int idx = blockIdx.x * 256 + threadIdx.x;
  int n = idx & 127, p = (idx >> 7) & 63, h = (idx >> 13) & 31, b = idx >> 18;
  float Nv = 0.f;
  for (int c = 0; c < 8; c++) {
    int bid = (b * 8 + c) * 32 + h;
    size_t addr = (size_t)bid * (HD * DST) + p * DST + n;
    float s = states[addr];
    states[addr] = Nv;
    Nv = Nv * expf((float)csum[bid]) + s;
  }
}

// ---------------- fused Y via split-bf16 MFMA, conflict-tuned staging ----------------
// block = (r, half): 1024 blocks, 4 waves, wave owns 32 l-rows.
__global__ void __launch_bounds__(256, 2) k_y5(const float* __restrict__ sx, const float* __restrict__ dtv,
                                               const double* __restrict__ acs, const float* __restrict__ prev,
                                               const float* __restrict__ zx, const float* __restrict__ Dp,
                                               const ushort_t* __restrict__ bhg, const ushort_t* __restrict__ blg,
                                               float* __restrict__ yg) {
  int bid = blockIdx.x;
  int r = bid >> 1, half = bid & 1;      // r = (b*8+c)*32+h
  int h = r & 31, bc = r >> 5;
  int t = threadIdx.x;
  int w = t >> 6, lane = t & 63;
  int l31 = lane & 31, lhf = lane >> 5;
  int lw = half * 128 + w * 32;          // wave's l-tile start within chunk

  __shared__ ushort_t Bh[32 * 132], Bl[32 * 132];   // B tile [s][n] bf16, pitch 132 (2-way reads)
  __shared__ float    Xs[32 * 69];                  // x tile [s][p] fp32, pitch 69
  __shared__ ushort_t Uh[64 * 36], Ul[64 * 36];     // u^T tile [p][s] bf16, pitch 36 (2-way)
  __shared__ ushort_t Sh[4][32 * 36], Sl[4][32 * 36]; // per-wave S' bf16 [l][s]
  __shared__ double   acs_s[256];

  acs_s[t] = acs[(size_t)r * 256 + t];
  __syncthreads();

  // C fragments in registers (split once per block)
  s8v Ch[8], Cl[8];
  {
    int tokl = bc * 256 + lw + l31;
    const float* Crow = sx + (size_t)tokl * CVD + DI + DST;
#pragma unroll
    for (int ks = 0; ks < 8; ++ks) {
      float4 a = *(const float4*)(Crow + ks * 16 + lhf * 8);
      float4 b = *(const float4*)(Crow + ks * 16 + lhf * 8 + 4);
      splitfrag(a, b, Ch[ks], Cl[ks]);
    }
  }

  // ---- Y_off FIRST: Yacc = C · prev^T, then scale rows by exp(acs_l) ----
  f16v Yacc[2] = {};
#pragma unroll
  for (int pt = 0; pt < 2; ++pt) {
    const float* pr = prev + (size_t)r * (HD * DST) + (size_t)(pt * 32 + l31) * DST;
#pragma unroll
    for (int ks = 0; ks < 8; ++ks) {
      float4 a = *(const float4*)(pr + ks * 16 + lhf * 8);
      float4 b = *(const float4*)(pr + ks * 16 + lhf * 8 + 4);
      s8v ph, pl;
      splitfrag(a, b, ph, pl);
      Yacc[pt] = __builtin_amdgcn_mfma_f32_32x32x16_bf16(Ch[ks], ph, Yacc[pt], 0, 0, 0);
      Yacc[pt] = __builtin_amdgcn_mfma_f32_32x32x16_bf16(Ch[ks], pl, Yacc[pt], 0, 0, 0);
      Yacc[pt] = __builtin_amdgcn_mfma_f32_32x32x16_bf16(Cl[ks], ph, Yacc[pt], 0, 0, 0);
    }
  }
#pragma unroll
  for (int rr = 0; rr < 16; ++rr) {
    int lrow = (rr & 3) + 8 * (rr >> 2) + 4 * lhf;
    float el = expf((float)acs_s[lw + lrow]);
    Yacc[0][rr] *= el;
    Yacc[1][rr] *= el;
  }

  // ---- main loop over 32-wide s subtiles ----
  int nsub = half * 4 + 4;
  for (int st = 0; st < nsub; ++st) {
    int s0 = st * 32;
    __syncthreads();   // protect prev-iter reads
    // stage B: direct b64 copies from precomputed global split (16 ushorts/thread)
    {
      int row = t >> 3, k = t & 7;
      size_t gbase = (size_t)(bc * 256 + s0 + row) * 128 + k * 16;
      const uint2* sh0 = (const uint2*)(bhg + gbase);
      uint2* dh = (uint2*)(&Bh[row * 132 + k * 16]);
      dh[0] = sh0[0]; dh[1] = sh0[1]; dh[2] = sh0[2]; dh[3] = sh0[3];
      const uint2* sl0 = (const uint2*)(blg + gbase);
      uint2* dl = (uint2*)(&Bl[row * 132 + k * 16]);
      dl[0] = sl0[0]; dl[1] = sl0[1]; dl[2] = sl0[2]; dl[3] = sl0[3];
    }
    // stage x fp32 row-major [s][p]
    {
      int srow = t >> 3, pg = (t & 7) * 8;
      const float* xr = sx + (size_t)(bc * 256 + s0 + srow) * CVD + h * 64 + pg;
      float4 v0 = *(const float4*)(xr);
      float4 v1 = *(const float4*)(xr + 4);
      float* dst = &Xs[srow * 69 + pg];
      dst[0] = v0.x; dst[1] = v0.y; dst[2] = v0.z; dst[3] = v0.w;
      dst[4] = v1.x; dst[5] = v1.y; dst[6] = v1.z; dst[7] = v1.w;
    }
    __syncthreads();   // stage visible
    // transpose + split x -> Uh/Ul [p][s]
    {
      int p = t >> 2, sg = (t & 3) * 8;
      ushort_t hh[8], ll[8];
#pragma unroll
      for (int j = 0; j < 8; j++) {
        float f = Xs[(sg + j) * 69 + p];
        hh[j] = f2bf(f);
        ll[j] = f2bf(f - bf2f(hh[j]));
      }
      uint2 hv0, hv1, lv0, lv1;
      hv0.x = (unsigned)hh[0] | ((unsigned)hh[1] << 16); hv0.y = (unsigned)hh[2] | ((unsigned)hh[3] << 16);
      hv1.x = (unsigned)hh[4] | ((unsigned)hh[5] << 16); hv1.y = (unsigned)hh[6] | ((unsigned)hh[7] << 16);
      lv0.x = (unsigned)ll[0] | ((unsigned)ll[1] << 16); lv0.y = (unsigned)ll[2] | ((unsigned)ll[3] << 16);
      lv1.x = (unsigned)ll[4] | ((unsigned)ll[5] << 16); lv1.y = (unsigned)ll[6] | ((unsigned)ll[7] << 16);
      *(uint2*)(&Uh[p * 36 + sg])     = hv0;
      *(uint2*)(&Uh[p * 36 + sg + 4]) = hv1;
      *(uint2*)(&Ul[p * 36 + sg])     = lv0;
      *(uint2*)(&Ul[p * 36 + sg + 4]) = lv1;
    }

    bool active = (s0 <= lw + 31);
    if (active) {
      // S-phase: Sacc[l][s] = sum_n C[l][n] * B[s][n]
      f16v Sacc = {};
#pragma unroll
      for (int ks = 0; ks < 8; ++ks) {
        union { s8v v; uint2 d[2]; } bh_, bl_;
        bh_.d[0] = *(const uint2*)(&Bh[l31 * 132 + ks * 16 + lhf * 8]);
        bh_.d[1] = *(const uint2*)(&Bh[l31 * 132 + ks * 16 + lhf * 8 + 4]);
        bl_.d[0] = *(const uint2*)(&Bl[l31 * 132 + ks * 16 + lhf * 8]);
        bl_.d[1] = *(const uint2*)(&Bl[l31 * 132 + ks * 16 + lhf * 8 + 4]);
        Sacc = __builtin_amdgcn_mfma_f32_32x32x16_bf16(Ch[ks], bh_.v, Sacc, 0, 0, 0);
        Sacc = __builtin_amdgcn_mfma_f32_32x32x16_bf16(Ch[ks], bl_.v, Sacc, 0, 0, 0);
        Sacc = __builtin_amdgcn_mfma_f32_32x32x16_bf16(Cl[ks], bh_.v, Sacc, 0, 0, 0);
      }
      // epilogue: decay * mask * dt -> bf16 hi/lo to per-wave LDS
      int sg2 = s0 + l31;
      float dts = dtv[(size_t)(bc * 256 + sg2) * 32 + h];
      double a_s = acs_s[sg2];
#pragma unroll
      for (int rr = 0; rr < 16; ++rr) {
        int lrow = (rr & 3) + 8 * (rr >> 2) + 4 * lhf;
        int lg = lw + lrow;
        float v = 0.f;
        if (sg2 <= lg) v = expf((float)(acs_s[lg] - a_s)) * Sacc[rr] * dts;
        ushort_t hh = f2bf(v);
        Sh[w][lrow * 36 + l31] = hh;
        Sl[w][lrow * 36 + l31] = f2bf(v - bf2f(hh));
      }
    }
    __syncthreads();   // Uh/Ul visible (Sh per-wave: in-wave ordering suffices)
    if (active) {
      // G2: Yacc += S' * u
#pragma unroll
      for (int ks2 = 0; ks2 < 2; ++ks2) {
        union { s8v v; uint2 d[2]; } sah, sal;
        sah.d[0] = *(const uint2*)(&Sh[w][l31 * 36 + ks2 * 16 + lhf * 8]);
        sah.d[1] = *(const uint2*)(&Sh[w][l31 * 36 + ks2 * 16 + lhf * 8 + 4]);
        sal.d[0] = *(const uint2*)(&Sl[w][l31 * 36 + ks2 * 16 + lhf * 8]);
        sal.d[1] = *(const uint2*)(&Sl[w][l31 * 36 + ks2 * 16 + lhf * 8 + 4]);
#pragma unroll
        for (int pt = 0; pt < 2; ++pt) {
          union { s8v v; uint2 d[2]; } uh, ul;
          uh.d[0] = *(const uint2*)(&Uh[(pt * 32 + l31) * 36 + ks2 * 16 + lhf * 8]);
          uh.d[1] = *(const uint2*)(&Uh[(pt * 32 + l31) * 36 + ks2 * 16 + lhf * 8 + 4]);
          ul.d[0] = *(const uint2*)(&Ul[(pt * 32 + l31) * 36 + ks2 * 16 + lhf * 8]);
          ul.d[1] = *(const uint2*)(&Ul[(pt * 32 + l31) * 36 + ks2 * 16 + lhf * 8 + 4]);
          Yacc[pt] = __builtin_amdgcn_mfma_f32_32x32x16_bf16(sah.v, uh.v, Yacc[pt], 0, 0, 0);
          Yacc[pt] = __builtin_amdgcn_mfma_f32_32x32x16_bf16(sah.v, ul.v, Yacc[pt], 0, 0, 0);
          Yacc[pt] = __builtin_amdgcn_mfma_f32_32x32x16_bf16(sal.v, uh.v, Yacc[pt], 0, 0, 0);
        }
      }
    }
  }

  // ---- epilogue: + x*Dp, gate silu(z), store ----
  float dph = Dp[h];
#pragma unroll
  for (int pt = 0; pt < 2; ++pt) {
    int p = pt * 32 + l31;
#pragma unroll
    for (int rr = 0; rr < 16; ++rr) {
      int lrow = (rr & 3) + 8 * (rr >> 2) + 4 * lhf;
      size_t tok = (size_t)(bc * 256 + lw + lrow);
      float xv = sx[tok * CVD + h * 64 + p];
      float zv = zx[tok * DIP + h * 64 + p];
      float y = (Yacc[pt][rr] + xv * dph) * (zv / (1.f + expf(-zv)));
      yg[tok * DI + h * 64 + p] = y;
    }
  }
}

// ---------------- launch ----------------
extern "C" void kernel_launch(void* const* d_in, const int* in_sizes, int n_in,
                              void* d_out, int out_size, void* d_ws, size_t ws_size,
                              hipStream_t stream) {
  const float* hidden   = (const float*)d_in[0];
  const float* norm_w   = (const float*)d_in[1];
  const float* in_proj  = (const float*)d_in[2];
  const float* conv_w   = (const float*)d_in[3];
  const float* conv_b   = (const float*)d_in[4];
  const float* A_log    = (const float*)d_in[5];
  const float* Dp       = (const float*)d_in[6];
  const float* dt_bias  = (const float*)d_in[7];
  const float* out_norm = (const float*)d_in[8];
  const float* out_proj = (const float*)d_in[9];
  float* out = (float*)d_out;

  char* ws = (char*)d_ws;
  float*  zx    = (float*)(ws + OFF_ZX);
  float*  sx    = (float*)(ws + OFF_SX);
  float*  st    = (float*)(ws + OFF_ST);
  float*  yg    = (float*)(ws + OFF_YG);
  int8_t* q1    = (int8_t*)(ws + OFF_Q1);
  int8_t* q2    = (int8_t*)(ws + OFF_Q2);
  int8_t* wq1   = (int8_t*)(ws + OFF_WQ1);
  int8_t* wq2   = (int8_t*)(ws + OFF_WQ2);
  float*  rs1   = (float*)(ws + OFF_RS1);
  float*  rs2   = (float*)(ws + OFF_RS2);
  float*  dtv   = (float*)(ws + OFF_DT);
  double* acs   = (double*)(ws + OFF_ACS);
  double* csum  = (double*)(ws + OFF_CSUM);
  double* part  = (double*)(ws + OFF_PART);
  double* wsc   = (double*)(ws + OFF_WSC);
  ushort_t* bhg = (ushort_t*)(ws + OFF_BH);
  ushort_t* blg = (ushort_t*)(ws + OFF_BL);

  const int n1 = DIP * DM, n2 = DM * DI;

  hipLaunchKernelGGL(k_absmean, dim3(512), dim3(256), 0, stream, in_proj, n1, part);
  hipLaunchKernelGGL(k_absmean, dim3(512), dim3(256), 0, stream, out_proj, n2, part + 512);
  hipLaunchKernelGGL(k_wscale, dim3(1), dim3(256), 0, stream, part, wsc, n1, n2);
  hipLaunchKernelGGL(k_tern, dim3((n1 + 255) / 256), dim3(256), 0, stream, in_proj, n1, wsc, 0, wq1);
  hipLaunchKernelGGL(k_tern, dim3((n2 + 255) / 256), dim3(256), 0, stream, out_proj, n2, wsc, 1, wq2);
  hipLaunchKernelGGL(k_normquant<DM>, dim3(TOKS), dim3(256), 0, stream, hidden, norm_w, q1, rs1);
  hipLaunchKernelGGL(k_gemm_mfma, dim3(TOKS / 128, (DIP + 127) / 128), dim3(256), 0, stream,
                     q1, wq1, rs1, (const float*)nullptr, zx, TOKS, DIP, DM);
  hipLaunchKernelGGL(k_conv, dim3(CVD / 256, TOKS), dim3(256), 0, stream, zx, conv_w, conv_b, sx);
  hipLaunchKernelGGL(k_splitb, dim3(512), dim3(256), 0, stream, sx, bhg, blg);
  hipLaunchKernelGGL(k_dt, dim3(TOKS * NH / 256), dim3(256), 0, stream, zx, dt_bias, dtv);
  hipLaunchKernelGGL(k_cumsum, dim3(512), dim3(256), 0, stream, dtv, A_log, acs, csum);
  hipLaunchKernelGGL(k_states2, dim3(512), dim3(256), 0, stream, sx, dtv, acs, csum, st);
  hipLaunchKernelGGL(k_chunkscan, dim3(2 * NH * HD * DST / 256), dim3(256), 0, stream, st, csum);
  hipLaunchKernelGGL(k_y5, dim3(1024), dim3(256), 0, stream, sx, dtv, acs, st, zx, Dp, bhg, blg, yg);
  hipLaunchKernelGGL(k_normquant<DI>, dim3(TOKS), dim3(256), 0, stream, yg, out_norm, q2, rs2);
  hipLaunchKernelGGL(k_gemm_mfma, dim3(TOKS / 128, DM / 128), dim3(256), 0, stream,
                     q2, wq2, rs2, hidden, out, TOKS, DM, DI);
  (void)in_sizes; (void)n_in; (void)out_size; (void)ws_size;
}